// Round 6
// baseline (7091.136 us; speedup 1.0000x reference)
//
#include <hip/hip_runtime.h>
#include <hip/hip_bf16.h>
#include <math.h>

// ---------------------------------------------------------------------------
// 2-layer tanh RNN, B=64 S=512 I=256 H=512, fp32 in/out, bf16 MFMA compute.
// Round 6: fused persistent scan, 16 blocks = 4 batch-groups x 4 col-slices.
// ALL THREE weight matrices (Whh0, Wih1, Whh1) fully register-resident
// (192 VGPR/thread). Merged h0+h1 exchange: one flag post / one poll per
// partner per iteration. Lag-1 pipeline:
//   iter i (0..512): L0 step t=i (i<=511), L1 step s=i-1 (i>=1)
//     A: poll flags>=i (partner h0_i, h1_{i-2} posted end of iter i-1); barrier
//     B: issue partner loads (hex slot i&1, both layers) + pre_i
//     early: own-k-tile MFMAs (own cols need no exchange)
//     D: commit partner data to LDS slot i&1; barrier
//     main: remaining 12 k-tiles for acc0/acc1
//     E: h0_{i+1} = tanh(acc0+pre_i) -> LDS slot (i+1)&1 + hex slot (i+1)&1
//     F: h1_{i-1} = tanh(acc1+b1)    -> LDS slot (i+1)&1 + hex slot (i+1)&1
//     G: barrier (drains stores); wave0 posts flags[blk] = i+1
//
// ws layout (bytes):
//   [0)        Wp_hh0  bf16 packed  512 KB
//   [524288)   Wp_hh1  bf16 packed  512 KB
//   [1048576)  Wp_ih1  bf16 packed  512 KB
//   [1572864)  Wp_ih0  bf16 packed  256 KB
//   [1835008)  hex     2 slots x 4 g x 2 layers x 16 x 256 u32 = 256 KB
//   [2097152)  xb      bf16 [32768][256]  16 MB
//   [18874368) flags   [16] u32 (32 zeroed)
//   [52428800) pre     fp32 PACKED ((t*16+blk)*512+tid)*4+r   64 MB
// ---------------------------------------------------------------------------

typedef __attribute__((ext_vector_type(8))) short  short8;
typedef __attribute__((ext_vector_type(4))) float  floatx4;
typedef __attribute__((ext_vector_type(4))) unsigned int uintx4;

#define MFMA_BF16(a, b, c) __builtin_amdgcn_mfma_f32_16x16x32_bf16((a), (b), (c), 0, 0, 0)

// offsets in u16 units for bf16 regions
#define OFS_HH0   ((size_t)0)
#define OFS_HH1   ((size_t)262144)
#define OFS_IH1   ((size_t)524288)
#define OFS_IH0   ((size_t)786432)
#define OFS_XB    ((size_t)1048576)
#define HEX_BYTE   ((size_t)1835008)
#define FLAGS_BYTE ((size_t)18874368)
#define PRE_B      ((size_t)52428800)

__device__ __forceinline__ unsigned short f2bf(float f) {
    unsigned u = __builtin_bit_cast(unsigned, f);
    u += 0x7fffu + ((u >> 16) & 1u);          // round-to-nearest-even
    return (unsigned short)(u >> 16);
}
__device__ __forceinline__ float bf2f(unsigned short h) {
    return __builtin_bit_cast(float, ((unsigned)h) << 16);
}
__device__ __forceinline__ float fast_tanh(float x) {
    float z = fminf(9.0f, fmaxf(-9.0f, x));
    float e = __builtin_amdgcn_exp2f(z * 2.88539008f);   // e^{2z}
    return (e - 1.0f) * __builtin_amdgcn_rcpf(e + 1.0f);
}

// ---- prep: pack weights into MFMA B-fragment order + convert x + flags ----
__device__ __forceinline__ void pack_w(const float* __restrict__ W,
                                       unsigned short* __restrict__ Wp,
                                       int KT, int idx) {
    int l  = idx & 63;
    int kt = (idx >> 6) % KT;
    int nt = (idx >> 6) / KT;
    int Kdim = KT * 32;
    int row = nt * 16 + (l & 15);
    int col = kt * 32 + (l >> 4) * 8;
    const float* s = W + (size_t)row * Kdim + col;
    short8 v;
#pragma unroll
    for (int j = 0; j < 8; ++j) v[j] = (short)f2bf(s[j]);
    *(short8*)(Wp + (size_t)idx * 8) = v;
}

__global__ void prep_kernel(const float* __restrict__ x,
                            const float* __restrict__ whh0,
                            const float* __restrict__ whh1,
                            const float* __restrict__ wih1,
                            const float* __restrict__ wih0,
                            unsigned short* __restrict__ wsb) {
    int blk = blockIdx.x, tid = threadIdx.x;
    if (blk < 128) {
        pack_w(whh0, wsb + OFS_HH0, 16, blk * 256 + tid);
    } else if (blk < 256) {
        pack_w(whh1, wsb + OFS_HH1, 16, (blk - 128) * 256 + tid);
    } else if (blk < 384) {
        pack_w(wih1, wsb + OFS_IH1, 16, (blk - 256) * 256 + tid);
    } else if (blk < 448) {
        pack_w(wih0, wsb + OFS_IH0, 8, (blk - 384) * 256 + tid);
    } else if (blk < 4544) {
        size_t e = ((size_t)(blk - 448) * 256 + tid) * 8;
        const float* s = x + e;
        short8 v;
#pragma unroll
        for (int j = 0; j < 8; ++j) v[j] = (short)f2bf(s[j]);
        *(short8*)(wsb + OFS_XB + e) = v;
    } else {
        if (tid < 32) ((unsigned int*)((char*)wsb + FLAGS_BYTE))[tid] = 0u;
    }
}

// ---- proj: pre0 = xb @ W_ih0^T + b_ih0 + b_hh0 -> fp32, PACKED for fused --
__global__ __launch_bounds__(512) void proj_kernel(
        const unsigned short* __restrict__ A,
        const unsigned short* __restrict__ Wp,
        const float* __restrict__ bias1, const float* __restrict__ bias2,
        float* __restrict__ out, int KT, int remap) {
    int tid = threadIdx.x, blk = blockIdx.x;
    int w = tid >> 6, l = tid & 63, lm = l & 15, lq = l >> 4;
    int mg = w >> 1, nh = w & 1;
    int Kdim = KT * 32;
    int r0 = blk * 64 + mg * 16;

    floatx4 acc[16];
#pragma unroll
    for (int i = 0; i < 16; ++i) acc[i] = (floatx4)0.f;

    for (int kt = 0; kt < KT; ++kt) {
        short8 a = *(const short8*)(A + (size_t)(r0 + lm) * Kdim + kt * 32 + lq * 8);
#pragma unroll
        for (int i = 0; i < 16; ++i) {
            int ntg = nh * 16 + i;
            short8 b = *(const short8*)(Wp + (((size_t)ntg * KT + kt) * 64 + l) * 8);
            acc[i] = MFMA_BF16(a, b, acc[i]);
        }
    }
#pragma unroll
    for (int i = 0; i < 16; ++i) {
        int n = (nh * 16 + i) * 16 + lm;
        float bs = bias1[n] + bias2[n];
        int slice2 = n >> 7, w2 = (n >> 4) & 7, lm2 = n & 15;
#pragma unroll
        for (int r = 0; r < 4; ++r) {
            int row = r0 + lq * 4 + r;
            int tt, b;
            if (remap) { b = row >> 9; tt = row & 511; }
            else       { tt = row >> 6; b = row & 63; }
            int g2 = b >> 4, br = b & 15;
            int tid2 = w2 * 64 + (br >> 2) * 16 + lm2;
            size_t idx = (((size_t)tt * 16 + g2 * 4 + slice2) * 512 + tid2) * 4 + (br & 3);
            out[idx] = acc[i][r] + bs;
        }
    }
}

// ---- fused 2-layer scan: 16 blocks = 4 groups x 4 slices -----------------
__global__ __launch_bounds__(512, 2) void fused_kernel(
        const float* __restrict__ pre,           // packed fp32 (layer-0 input proj)
        const unsigned short* __restrict__ Whh0, // packed bf16 KT=16
        const unsigned short* __restrict__ Whh1,
        const unsigned short* __restrict__ Wih1,
        unsigned int* __restrict__ hex,          // merged exchange, u32 col-pairs
        unsigned int* __restrict__ flags,        // [16]
        const float* __restrict__ bih1, const float* __restrict__ bhh1,
        const float* __restrict__ wfc, const float* __restrict__ bfc,
        float* __restrict__ out) {
    __shared__ unsigned short h0[2][16][512];       // 32 KB, XOR-swizzled chunks
    __shared__ unsigned short h1[2][16][512];       // 32 KB

    const int tid = threadIdx.x;
    const int w = tid >> 6, l = tid & 63, lm = l & 15, lq = l >> 4;
    const int blk = blockIdx.x, g = blk >> 2, slice = blk & 3;
    const int ntg = slice * 8 + w;            // global 16-col tile
    const int ncol = ntg * 16 + lm;           // global col this thread produces
    const int s4 = slice * 4;                 // own k-tile range [s4, s4+4)

    // zero all h state (t<0 states and partner regions)
    {
        uintx4* z0 = (uintx4*)&h0[0][0][0];
        uintx4* z1 = (uintx4*)&h1[0][0][0];
        for (int i = tid; i < 2048; i += 512) { z0[i] = (uintx4)0u; z1[i] = (uintx4)0u; }
    }
    // ALL THREE weight matrices register-resident: 48 short8 = 192 VGPR
    short8 breg0[16], bregI[16], breg1[16];
#pragma unroll
    for (int kt = 0; kt < 16; ++kt) {
        size_t src = (((size_t)ntg * 16 + kt) * 64 + l) * 8;
        breg0[kt] = *(const short8*)(Whh0 + src);
        bregI[kt] = *(const short8*)(Wih1 + src);
        breg1[kt] = *(const short8*)(Whh1 + src);
    }
    const float b1v = bih1[ncol] + bhh1[ncol];
    __syncthreads();

    // exchange-phase constants
    const int rrow = tid >> 5;
    const int cgrp = tid & 31;
    const bool dl = (cgrp >> 3) != slice;          // partner columns only
    const int pc0 = ((cgrp * 2) ^ (rrow & 7));
    const int pc1 = ((cgrp * 2 + 1) ^ (rrow & 7));
    const bool pl0 = (l == 0) && (w >= 1) && (w <= 3);
    const int ps0 = (slice + w) & 3;
    // own-col write address pieces (u32 pair writes, even-lm lanes)
    const int mychunk = ncol >> 3;

    for (int i = 0; i <= 512; ++i) {
        const int sl = i & 1, slw = sl ^ 1;

        // --- A: one poll per partner (covers both layers) ---
        if (pl0 && i >= 1) {
            unsigned int tgt = (unsigned int)i;
            while (__hip_atomic_load(&flags[g * 4 + ps0],
                                     __ATOMIC_ACQUIRE, __HIP_MEMORY_SCOPE_AGENT) < tgt)
                __builtin_amdgcn_s_sleep(2);
        }
        __syncthreads();

        // --- B: issue partner loads + pre ---
        const bool ld0 = dl && (i >= 1);
        const bool ld1 = dl && (i >= 2);
        uintx4 v0a, v0b, v1a, v1b;
        if (ld0) {
            const uintx4* s = (const uintx4*)(hex + (size_t)((sl * 4 + g) * 2 + 0) * 4096
                                              + rrow * 256 + cgrp * 8);
            v0a = s[0]; v0b = s[1];
        }
        if (ld1) {
            const uintx4* s = (const uintx4*)(hex + (size_t)((sl * 4 + g) * 2 + 1) * 4096
                                              + rrow * 256 + cgrp * 8);
            v1a = s[0]; v1b = s[1];
        }
        floatx4 pv = (floatx4)0.f;
        if (i <= 511)
            pv = *(const floatx4*)(pre + (((size_t)i * 16 + blk) * 512 + tid) * 4);

        // --- early: own-k-tile MFMAs (own cols never need the exchange) ---
        floatx4 acc0 = (floatx4)0.f, acc1 = (floatx4)0.f;
#pragma unroll
        for (int j = 0; j < 4; ++j) {
            int kt = s4 + j;
            int ch = ((kt * 4 + lq) ^ (lm & 7)) << 3;
            short8 a = *(const short8*)&h0[sl][lm][ch];
            acc0 = MFMA_BF16(a, breg0[kt], acc0);
            acc1 = MFMA_BF16(a, bregI[kt], acc1);
            short8 a1 = *(const short8*)&h1[sl][lm][ch];
            acc1 = MFMA_BF16(a1, breg1[kt], acc1);
        }

        // --- D: commit partner data ---
        if (ld0) {
            *(uintx4*)&h0[sl][rrow][pc0 * 8] = v0a;
            *(uintx4*)&h0[sl][rrow][pc1 * 8] = v0b;
        }
        if (ld1) {
            *(uintx4*)&h1[sl][rrow][pc0 * 8] = v1a;
            *(uintx4*)&h1[sl][rrow][pc1 * 8] = v1b;
        }
        __syncthreads();

        // --- main: remaining 12 k-tiles ---
#pragma unroll
        for (int j = 4; j < 16; ++j) {
            int kt = (s4 + j) & 15;
            int ch = ((kt * 4 + lq) ^ (lm & 7)) << 3;
            short8 a = *(const short8*)&h0[sl][lm][ch];
            acc0 = MFMA_BF16(a, breg0[kt], acc0);
            acc1 = MFMA_BF16(a, bregI[kt], acc1);
            short8 a1 = *(const short8*)&h1[sl][lm][ch];
            acc1 = MFMA_BF16(a1, breg1[kt], acc1);
        }

        // --- E: layer-0 step i -> h0_{i+1} ---
        if (i <= 511) {
            unsigned int* exw = hex + (size_t)((slw * 4 + g) * 2 + 0) * 4096;
#pragma unroll
            for (int r = 0; r < 4; ++r) {
                int row = lq * 4 + r;
                unsigned int hb = f2bf(fast_tanh(acc0[r] + pv[r]));
                unsigned int pk = hb | ((unsigned int)__shfl_xor((int)hb, 1) << 16);
                if (!(lm & 1)) {
                    *(unsigned int*)&h0[slw][row][((mychunk ^ (row & 7)) << 3) | (ncol & 7)] = pk;
                    exw[(size_t)row * 256 + (ncol >> 1)] = pk;
                }
            }
        }

        // --- F: layer-1 step i-1 -> h1_{i-1} ---
        if (i >= 1) {
            unsigned int* exw = hex + (size_t)((slw * 4 + g) * 2 + 1) * 4096;
#pragma unroll
            for (int r = 0; r < 4; ++r) {
                int row = lq * 4 + r;
                unsigned int hb = f2bf(fast_tanh(acc1[r] + b1v));
                unsigned int pk = hb | ((unsigned int)__shfl_xor((int)hb, 1) << 16);
                if (!(lm & 1)) {
                    *(unsigned int*)&h1[slw][row][((mychunk ^ (row & 7)) << 3) | (ncol & 7)] = pk;
                    exw[(size_t)row * 256 + (ncol >> 1)] = pk;
                }
            }
        }

        __syncthreads();   // drains vmcnt before release post

        // --- G: single post covering both layers ---
        if (tid == 0)
            __hip_atomic_fetch_add(&flags[blk], 1u,
                                   __ATOMIC_RELEASE, __HIP_MEMORY_SCOPE_AGENT);
    }

    // --- FC head: slice-0 blocks gather full h1_511 and reduce ---
    if (slice == 0) {
        if (pl0) {   // final post value is 513
            while (__hip_atomic_load(&flags[g * 4 + ps0],
                                     __ATOMIC_ACQUIRE, __HIP_MEMORY_SCOPE_AGENT) < 513u)
                __builtin_amdgcn_s_sleep(2);
        }
        __syncthreads();
        if (dl) {    // h1_511 lives in hex slot 1, layer 1
            const uintx4* s = (const uintx4*)(hex + (size_t)((1 * 4 + g) * 2 + 1) * 4096
                                              + rrow * 256 + cgrp * 8);
            uintx4 a = s[0], b = s[1];
            *(uintx4*)&h1[1][rrow][pc0 * 8] = a;
            *(uintx4*)&h1[1][rrow][pc1 * 8] = b;
        }
        __syncthreads();
        if (tid < 160) {
            int b = tid / 10, c = tid % 10;
            float s = bfc[c];
            for (int n = 0; n < 512; ++n) {
                unsigned short hb = h1[1][b][(((n >> 3) ^ (b & 7)) << 3) | (n & 7)];
                s += bf2f(hb) * wfc[c * 512 + n];
            }
            out[(size_t)(g * 16 + b) * 10 + c] = s;
        }
    }
}

extern "C" void kernel_launch(void* const* d_in, const int* in_sizes, int n_in,
                              void* d_out, int out_size, void* d_ws, size_t ws_size,
                              hipStream_t stream) {
    const float* x    = (const float*)d_in[0];
    const float* wih0 = (const float*)d_in[1];
    const float* whh0 = (const float*)d_in[2];
    const float* bih0 = (const float*)d_in[3];
    const float* bhh0 = (const float*)d_in[4];
    const float* wih1 = (const float*)d_in[5];
    const float* whh1 = (const float*)d_in[6];
    const float* bih1 = (const float*)d_in[7];
    const float* bhh1 = (const float*)d_in[8];
    const float* wfc  = (const float*)d_in[9];
    const float* bfc  = (const float*)d_in[10];
    float* out = (float*)d_out;

    unsigned short* wsb  = (unsigned short*)d_ws;
    unsigned short* xb   = wsb + OFS_XB;
    unsigned int* hex    = (unsigned int*)((char*)d_ws + HEX_BYTE);
    unsigned int* flags  = (unsigned int*)((char*)d_ws + FLAGS_BYTE);
    float* pre = (float*)((char*)d_ws + PRE_B);

    // 1. pack weights + convert x + zero flags
    prep_kernel<<<dim3(4545), dim3(256), 0, stream>>>(x, whh0, whh1, wih1, wih0, wsb);
    // 2. pre0 = x @ w_ih0^T + b_ih0 + b_hh0  (packed for fused kernel)
    proj_kernel<<<dim3(512), dim3(512), 0, stream>>>(xb, wsb + OFS_IH0, bih0, bhh0, pre, 8, 1);
    // 3. fused 2-layer scan + FC head
    fused_kernel<<<dim3(16), dim3(512), 0, stream>>>(
        pre, wsb + OFS_HH0, wsb + OFS_HH1, wsb + OFS_IH1,
        hex, flags, bih1, bhh1, wfc, bfc, out);
}

// Round 7
// 3111.920 us; speedup vs baseline: 2.2787x; 2.2787x over previous
//
#include <hip/hip_runtime.h>
#include <hip/hip_bf16.h>
#include <math.h>

// ---------------------------------------------------------------------------
// 2-layer tanh RNN, B=64 S=512 I=256 H=512, fp32 in/out, bf16 MFMA compute.
// Round 7: R6 structure with the register-sinking bug fixed. The three
// weight matrices (Whh0, Wih1, Whh1) are register-resident as PRE-ROTATED
// arrays: breg?[j] holds k-tile (slice*4+j)&15, so every in-loop index is a
// compile-time literal after unroll (R6's runtime `(s4+j)&15` index forced
// the compiler to dissolve the arrays into per-iteration global loads --
// VGPR_Count 64 instead of ~230, 2x regression).
//
// 16 blocks = 4 batch-groups x 4 col-slices. Merged h0+h1 exchange, one
// flag post / one poll per partner per iteration, lag-1 pipeline:
//   iter i (0..512): L0 step t=i (i<=511), L1 step s=i-1 (i>=1)
//     A: poll flags>=i; barrier
//     B: issue partner loads (hex slot i&1) + pre_i
//     early: own k-tiles j=0..3 (own cols need no exchange data)
//     D: commit partner data to LDS slot i&1; barrier
//     main: k-tiles j=4..15
//     E/F: tanh -> LDS slot (i+1)&1 + hex slot (i+1)&1 (u32 col-pair writes)
//     G: barrier (drains stores); wave0 posts flags[blk] = i+1
//
// ws layout (bytes):
//   [0)        Wp_hh0  bf16 packed  512 KB
//   [524288)   Wp_hh1  bf16 packed  512 KB
//   [1048576)  Wp_ih1  bf16 packed  512 KB
//   [1572864)  Wp_ih0  bf16 packed  256 KB
//   [1835008)  hex     2 slots x 4 g x 2 layers x 16 x 256 u32 = 256 KB
//   [2097152)  xb      bf16 [32768][256]  16 MB
//   [18874368) flags   [16] u32 (32 zeroed)
//   [52428800) pre     fp32 PACKED ((t*16+blk)*512+tid)*4+r   64 MB
// ---------------------------------------------------------------------------

typedef __attribute__((ext_vector_type(8))) short  short8;
typedef __attribute__((ext_vector_type(4))) float  floatx4;
typedef __attribute__((ext_vector_type(4))) unsigned int uintx4;

#define MFMA_BF16(a, b, c) __builtin_amdgcn_mfma_f32_16x16x32_bf16((a), (b), (c), 0, 0, 0)

// offsets in u16 units for bf16 regions
#define OFS_HH0   ((size_t)0)
#define OFS_HH1   ((size_t)262144)
#define OFS_IH1   ((size_t)524288)
#define OFS_IH0   ((size_t)786432)
#define OFS_XB    ((size_t)1048576)
#define HEX_BYTE   ((size_t)1835008)
#define FLAGS_BYTE ((size_t)18874368)
#define PRE_B      ((size_t)52428800)

__device__ __forceinline__ unsigned short f2bf(float f) {
    unsigned u = __builtin_bit_cast(unsigned, f);
    u += 0x7fffu + ((u >> 16) & 1u);          // round-to-nearest-even
    return (unsigned short)(u >> 16);
}
__device__ __forceinline__ float bf2f(unsigned short h) {
    return __builtin_bit_cast(float, ((unsigned)h) << 16);
}
__device__ __forceinline__ float fast_tanh(float x) {
    float z = fminf(9.0f, fmaxf(-9.0f, x));
    float e = __builtin_amdgcn_exp2f(z * 2.88539008f);   // e^{2z}
    return (e - 1.0f) * __builtin_amdgcn_rcpf(e + 1.0f);
}

// ---- prep: pack weights into MFMA B-fragment order + convert x + flags ----
__device__ __forceinline__ void pack_w(const float* __restrict__ W,
                                       unsigned short* __restrict__ Wp,
                                       int KT, int idx) {
    int l  = idx & 63;
    int kt = (idx >> 6) % KT;
    int nt = (idx >> 6) / KT;
    int Kdim = KT * 32;
    int row = nt * 16 + (l & 15);
    int col = kt * 32 + (l >> 4) * 8;
    const float* s = W + (size_t)row * Kdim + col;
    short8 v;
#pragma unroll
    for (int j = 0; j < 8; ++j) v[j] = (short)f2bf(s[j]);
    *(short8*)(Wp + (size_t)idx * 8) = v;
}

__global__ void prep_kernel(const float* __restrict__ x,
                            const float* __restrict__ whh0,
                            const float* __restrict__ whh1,
                            const float* __restrict__ wih1,
                            const float* __restrict__ wih0,
                            unsigned short* __restrict__ wsb) {
    int blk = blockIdx.x, tid = threadIdx.x;
    if (blk < 128) {
        pack_w(whh0, wsb + OFS_HH0, 16, blk * 256 + tid);
    } else if (blk < 256) {
        pack_w(whh1, wsb + OFS_HH1, 16, (blk - 128) * 256 + tid);
    } else if (blk < 384) {
        pack_w(wih1, wsb + OFS_IH1, 16, (blk - 256) * 256 + tid);
    } else if (blk < 448) {
        pack_w(wih0, wsb + OFS_IH0, 8, (blk - 384) * 256 + tid);
    } else if (blk < 4544) {
        size_t e = ((size_t)(blk - 448) * 256 + tid) * 8;
        const float* s = x + e;
        short8 v;
#pragma unroll
        for (int j = 0; j < 8; ++j) v[j] = (short)f2bf(s[j]);
        *(short8*)(wsb + OFS_XB + e) = v;
    } else {
        if (tid < 32) ((unsigned int*)((char*)wsb + FLAGS_BYTE))[tid] = 0u;
    }
}

// ---- proj: pre0 = xb @ W_ih0^T + b_ih0 + b_hh0 -> fp32, PACKED for fused --
__global__ __launch_bounds__(512) void proj_kernel(
        const unsigned short* __restrict__ A,
        const unsigned short* __restrict__ Wp,
        const float* __restrict__ bias1, const float* __restrict__ bias2,
        float* __restrict__ out, int KT, int remap) {
    int tid = threadIdx.x, blk = blockIdx.x;
    int w = tid >> 6, l = tid & 63, lm = l & 15, lq = l >> 4;
    int mg = w >> 1, nh = w & 1;
    int Kdim = KT * 32;
    int r0 = blk * 64 + mg * 16;

    floatx4 acc[16];
#pragma unroll
    for (int i = 0; i < 16; ++i) acc[i] = (floatx4)0.f;

    for (int kt = 0; kt < KT; ++kt) {
        short8 a = *(const short8*)(A + (size_t)(r0 + lm) * Kdim + kt * 32 + lq * 8);
#pragma unroll
        for (int i = 0; i < 16; ++i) {
            int ntg = nh * 16 + i;
            short8 b = *(const short8*)(Wp + (((size_t)ntg * KT + kt) * 64 + l) * 8);
            acc[i] = MFMA_BF16(a, b, acc[i]);
        }
    }
#pragma unroll
    for (int i = 0; i < 16; ++i) {
        int n = (nh * 16 + i) * 16 + lm;
        float bs = bias1[n] + bias2[n];
        int slice2 = n >> 7, w2 = (n >> 4) & 7, lm2 = n & 15;
#pragma unroll
        for (int r = 0; r < 4; ++r) {
            int row = r0 + lq * 4 + r;
            int tt, b;
            if (remap) { b = row >> 9; tt = row & 511; }
            else       { tt = row >> 6; b = row & 63; }
            int g2 = b >> 4, br = b & 15;
            int tid2 = w2 * 64 + (br >> 2) * 16 + lm2;
            size_t idx = (((size_t)tt * 16 + g2 * 4 + slice2) * 512 + tid2) * 4 + (br & 3);
            out[idx] = acc[i][r] + bs;
        }
    }
}

// ---- fused 2-layer scan: 16 blocks = 4 groups x 4 slices -----------------
__global__ __launch_bounds__(512, 2) void fused_kernel(
        const float* __restrict__ pre,           // packed fp32 (layer-0 input proj)
        const unsigned short* __restrict__ Whh0, // packed bf16 KT=16
        const unsigned short* __restrict__ Whh1,
        const unsigned short* __restrict__ Wih1,
        unsigned int* __restrict__ hex,          // merged exchange, u32 col-pairs
        unsigned int* __restrict__ flags,        // [16]
        const float* __restrict__ bih1, const float* __restrict__ bhh1,
        const float* __restrict__ wfc, const float* __restrict__ bfc,
        float* __restrict__ out) {
    __shared__ unsigned short h0[2][16][512];       // 32 KB, XOR-swizzled chunks
    __shared__ unsigned short h1[2][16][512];       // 32 KB

    const int tid = threadIdx.x;
    const int w = tid >> 6, l = tid & 63, lm = l & 15, lq = l >> 4;
    const int blk = blockIdx.x, g = blk >> 2, slice = blk & 3;
    const int ntg = slice * 8 + w;            // global 16-col tile
    const int ncol = ntg * 16 + lm;           // global col this thread produces
    const int s4 = slice * 4;                 // own k-tile range [s4, s4+4)

    // zero all h state (t<0 states and partner regions)
    {
        uintx4* z0 = (uintx4*)&h0[0][0][0];
        uintx4* z1 = (uintx4*)&h1[0][0][0];
        for (int i = tid; i < 2048; i += 512) { z0[i] = (uintx4)0u; z1[i] = (uintx4)0u; }
    }
    // Weights register-resident, PRE-ROTATED: breg?[j] = k-tile (s4+j)&15.
    // All in-loop indices are literals after unroll -> arrays stay in VGPRs.
    short8 breg0[16], bregI[16], breg1[16];
#pragma unroll
    for (int j = 0; j < 16; ++j) {
        int kt = (s4 + j) & 15;
        size_t src = (((size_t)ntg * 16 + kt) * 64 + l) * 8;
        breg0[j] = *(const short8*)(Whh0 + src);
        bregI[j] = *(const short8*)(Wih1 + src);
        breg1[j] = *(const short8*)(Whh1 + src);
    }
    const float b1v = bih1[ncol] + bhh1[ncol];
    __syncthreads();

    // exchange-phase constants
    const int rrow = tid >> 5;
    const int cgrp = tid & 31;
    const bool dl = (cgrp >> 3) != slice;          // partner columns only
    const int pc0 = ((cgrp * 2) ^ (rrow & 7));
    const int pc1 = ((cgrp * 2 + 1) ^ (rrow & 7));
    const bool pl0 = (l == 0) && (w >= 1) && (w <= 3);
    const int ps0 = (slice + w) & 3;
    const int mychunk = ncol >> 3;

    for (int i = 0; i <= 512; ++i) {
        const int sl = i & 1, slw = sl ^ 1;

        // --- A: one poll per partner (covers both layers) ---
        if (pl0 && i >= 1) {
            unsigned int tgt = (unsigned int)i;
            while (__hip_atomic_load(&flags[g * 4 + ps0],
                                     __ATOMIC_ACQUIRE, __HIP_MEMORY_SCOPE_AGENT) < tgt)
                __builtin_amdgcn_s_sleep(2);
        }
        __syncthreads();

        // --- B: issue partner loads + pre ---
        const bool ld0 = dl && (i >= 1);
        const bool ld1 = dl && (i >= 2);
        uintx4 v0a, v0b, v1a, v1b;
        if (ld0) {
            const uintx4* s = (const uintx4*)(hex + (size_t)((sl * 4 + g) * 2 + 0) * 4096
                                              + rrow * 256 + cgrp * 8);
            v0a = s[0]; v0b = s[1];
        }
        if (ld1) {
            const uintx4* s = (const uintx4*)(hex + (size_t)((sl * 4 + g) * 2 + 1) * 4096
                                              + rrow * 256 + cgrp * 8);
            v1a = s[0]; v1b = s[1];
        }
        floatx4 pv = (floatx4)0.f;
        if (i <= 511)
            pv = *(const floatx4*)(pre + (((size_t)i * 16 + blk) * 512 + tid) * 4);

        // --- early: own k-tiles j=0..3 (literal breg indices) ---
        floatx4 acc0 = (floatx4)0.f, acc1 = (floatx4)0.f;
#pragma unroll
        for (int j = 0; j < 4; ++j) {
            int kt = s4 + j;                       // == (s4+j)&15 for j<4
            int ch = ((kt * 4 + lq) ^ (lm & 7)) << 3;
            short8 a = *(const short8*)&h0[sl][lm][ch];
            acc0 = MFMA_BF16(a, breg0[j], acc0);
            acc1 = MFMA_BF16(a, bregI[j], acc1);
            short8 a1 = *(const short8*)&h1[sl][lm][ch];
            acc1 = MFMA_BF16(a1, breg1[j], acc1);
        }

        // --- D: commit partner data ---
        if (ld0) {
            *(uintx4*)&h0[sl][rrow][pc0 * 8] = v0a;
            *(uintx4*)&h0[sl][rrow][pc1 * 8] = v0b;
        }
        if (ld1) {
            *(uintx4*)&h1[sl][rrow][pc0 * 8] = v1a;
            *(uintx4*)&h1[sl][rrow][pc1 * 8] = v1b;
        }
        __syncthreads();

        // --- main: k-tiles j=4..15 (literal breg indices) ---
#pragma unroll
        for (int j = 4; j < 16; ++j) {
            int kt = (s4 + j) & 15;                // runtime value only in address
            int ch = ((kt * 4 + lq) ^ (lm & 7)) << 3;
            short8 a = *(const short8*)&h0[sl][lm][ch];
            acc0 = MFMA_BF16(a, breg0[j], acc0);
            acc1 = MFMA_BF16(a, bregI[j], acc1);
            short8 a1 = *(const short8*)&h1[sl][lm][ch];
            acc1 = MFMA_BF16(a1, breg1[j], acc1);
        }

        // --- E: layer-0 step i -> h0_{i+1} ---
        if (i <= 511) {
            unsigned int* exw = hex + (size_t)((slw * 4 + g) * 2 + 0) * 4096;
#pragma unroll
            for (int r = 0; r < 4; ++r) {
                int row = lq * 4 + r;
                unsigned int hb = f2bf(fast_tanh(acc0[r] + pv[r]));
                unsigned int pk = hb | ((unsigned int)__shfl_xor((int)hb, 1) << 16);
                if (!(lm & 1)) {
                    *(unsigned int*)&h0[slw][row][((mychunk ^ (row & 7)) << 3) | (ncol & 7)] = pk;
                    exw[(size_t)row * 256 + (ncol >> 1)] = pk;
                }
            }
        }

        // --- F: layer-1 step i-1 -> h1_{i-1} ---
        if (i >= 1) {
            unsigned int* exw = hex + (size_t)((slw * 4 + g) * 2 + 1) * 4096;
#pragma unroll
            for (int r = 0; r < 4; ++r) {
                int row = lq * 4 + r;
                unsigned int hb = f2bf(fast_tanh(acc1[r] + b1v));
                unsigned int pk = hb | ((unsigned int)__shfl_xor((int)hb, 1) << 16);
                if (!(lm & 1)) {
                    *(unsigned int*)&h1[slw][row][((mychunk ^ (row & 7)) << 3) | (ncol & 7)] = pk;
                    exw[(size_t)row * 256 + (ncol >> 1)] = pk;
                }
            }
        }

        __syncthreads();   // drains vmcnt before release post

        // --- G: single post covering both layers ---
        if (tid == 0)
            __hip_atomic_fetch_add(&flags[blk], 1u,
                                   __ATOMIC_RELEASE, __HIP_MEMORY_SCOPE_AGENT);
    }

    // --- FC head: slice-0 blocks gather full h1_511 and reduce ---
    if (slice == 0) {
        if (pl0) {   // final post value is 513
            while (__hip_atomic_load(&flags[g * 4 + ps0],
                                     __ATOMIC_ACQUIRE, __HIP_MEMORY_SCOPE_AGENT) < 513u)
                __builtin_amdgcn_s_sleep(2);
        }
        __syncthreads();
        if (dl) {    // h1_511 lives in hex slot 1, layer 1
            const uintx4* s = (const uintx4*)(hex + (size_t)((1 * 4 + g) * 2 + 1) * 4096
                                              + rrow * 256 + cgrp * 8);
            uintx4 a = s[0], b = s[1];
            *(uintx4*)&h1[1][rrow][pc0 * 8] = a;
            *(uintx4*)&h1[1][rrow][pc1 * 8] = b;
        }
        __syncthreads();
        if (tid < 160) {
            int b = tid / 10, c = tid % 10;
            float s = bfc[c];
            for (int n = 0; n < 512; ++n) {
                unsigned short hb = h1[1][b][(((n >> 3) ^ (b & 7)) << 3) | (n & 7)];
                s += bf2f(hb) * wfc[c * 512 + n];
            }
            out[(size_t)(g * 16 + b) * 10 + c] = s;
        }
    }
}

extern "C" void kernel_launch(void* const* d_in, const int* in_sizes, int n_in,
                              void* d_out, int out_size, void* d_ws, size_t ws_size,
                              hipStream_t stream) {
    const float* x    = (const float*)d_in[0];
    const float* wih0 = (const float*)d_in[1];
    const float* whh0 = (const float*)d_in[2];
    const float* bih0 = (const float*)d_in[3];
    const float* bhh0 = (const float*)d_in[4];
    const float* wih1 = (const float*)d_in[5];
    const float* whh1 = (const float*)d_in[6];
    const float* bih1 = (const float*)d_in[7];
    const float* bhh1 = (const float*)d_in[8];
    const float* wfc  = (const float*)d_in[9];
    const float* bfc  = (const float*)d_in[10];
    float* out = (float*)d_out;

    unsigned short* wsb  = (unsigned short*)d_ws;
    unsigned short* xb   = wsb + OFS_XB;
    unsigned int* hex    = (unsigned int*)((char*)d_ws + HEX_BYTE);
    unsigned int* flags  = (unsigned int*)((char*)d_ws + FLAGS_BYTE);
    float* pre = (float*)((char*)d_ws + PRE_B);

    // 1. pack weights + convert x + zero flags
    prep_kernel<<<dim3(4545), dim3(256), 0, stream>>>(x, whh0, whh1, wih1, wih0, wsb);
    // 2. pre0 = x @ w_ih0^T + b_ih0 + b_hh0  (packed for fused kernel)
    proj_kernel<<<dim3(512), dim3(512), 0, stream>>>(xb, wsb + OFS_IH0, bih0, bhh0, pre, 8, 1);
    // 3. fused 2-layer scan + FC head
    fused_kernel<<<dim3(16), dim3(512), 0, stream>>>(
        pre, wsb + OFS_HH0, wsb + OFS_HH1, wsb + OFS_IH1,
        hex, flags, bih1, bhh1, wfc, bfc, out);
}

// Round 8
// 3017.430 us; speedup vs baseline: 2.3501x; 1.0313x over previous
//
#include <hip/hip_runtime.h>
#include <hip/hip_bf16.h>
#include <math.h>

// ---------------------------------------------------------------------------
// 2-layer tanh RNN, B=64 S=512 I=256 H=512, fp32 in/out, bf16 MFMA compute.
// Round 8: 8-way column split so ALL weights fit in registers with slack.
// 32 blocks = 4 batch-groups x 8 col-slices, 256 threads (4 waves) per block,
// __launch_bounds__(256,1) -> 1 wave/SIMD -> 512-VGPR cap. Each wave owns
// one 16-col tile; bregs = 3 matrices x 16 kt x 4 VGPR = 192 regs (pre-
// rotated so all in-loop indices are literals). R7 failed residency because
// (512,2)'s 256-reg cap < 192+working-set; here cap is 512.
//
// Lag-1 pipeline per iter i (0..512): L0 step i (i<=511), L1 step i-1 (i>=1)
//   A: wave1 lanes0-6 poll 7 partner flags >= i; barrier
//   B: issue partner hex loads (all non-own chunks, both layers) + pre_i
//   early: own k-tiles j=0..1 (own cols already in LDS from prev iter)
//   D: commit partner data to LDS slot i&1; barrier
//   main: k-tiles j=2..15
//   E: h0_{i+1}=tanh(acc0+pre) -> LDS slot (i+1)&1 + hex slot (i+1)&1
//   F: h1_{i-1}=tanh(acc1+b1)  -> LDS slot (i+1)&1 + hex slot (i+1)&1
//   G: barrier (drains stores); wave0 lane0 posts flags[blk]=i+1
//
// ws layout (bytes):
//   [0)        Wp_hh0  bf16 packed  512 KB
//   [524288)   Wp_hh1  bf16 packed  512 KB
//   [1048576)  Wp_ih1  bf16 packed  512 KB
//   [1572864)  Wp_ih0  bf16 packed  256 KB
//   [1835008)  hex     2 slots x 4 g x 2 layers x 16 x 256 u32 = 256 KB
//   [2097152)  xb      bf16 [32768][256]  16 MB
//   [18874368) flags   [32] u32
//   [52428800) pre     fp32 PACKED ((t*32+blk)*256+tid)*4+r   64 MB
// ---------------------------------------------------------------------------

typedef __attribute__((ext_vector_type(8))) short  short8;
typedef __attribute__((ext_vector_type(4))) float  floatx4;
typedef __attribute__((ext_vector_type(4))) unsigned int uintx4;

#define MFMA_BF16(a, b, c) __builtin_amdgcn_mfma_f32_16x16x32_bf16((a), (b), (c), 0, 0, 0)

// offsets in u16 units for bf16 regions
#define OFS_HH0   ((size_t)0)
#define OFS_HH1   ((size_t)262144)
#define OFS_IH1   ((size_t)524288)
#define OFS_IH0   ((size_t)786432)
#define OFS_XB    ((size_t)1048576)
#define HEX_BYTE   ((size_t)1835008)
#define FLAGS_BYTE ((size_t)18874368)
#define PRE_B      ((size_t)52428800)

__device__ __forceinline__ unsigned short f2bf(float f) {
    unsigned u = __builtin_bit_cast(unsigned, f);
    u += 0x7fffu + ((u >> 16) & 1u);          // round-to-nearest-even
    return (unsigned short)(u >> 16);
}
__device__ __forceinline__ float bf2f(unsigned short h) {
    return __builtin_bit_cast(float, ((unsigned)h) << 16);
}
__device__ __forceinline__ float fast_tanh(float x) {
    float z = fminf(9.0f, fmaxf(-9.0f, x));
    float e = __builtin_amdgcn_exp2f(z * 2.88539008f);   // e^{2z}
    return (e - 1.0f) * __builtin_amdgcn_rcpf(e + 1.0f);
}

// ---- prep: pack weights into MFMA B-fragment order + convert x + flags ----
__device__ __forceinline__ void pack_w(const float* __restrict__ W,
                                       unsigned short* __restrict__ Wp,
                                       int KT, int idx) {
    int l  = idx & 63;
    int kt = (idx >> 6) % KT;
    int nt = (idx >> 6) / KT;
    int Kdim = KT * 32;
    int row = nt * 16 + (l & 15);
    int col = kt * 32 + (l >> 4) * 8;
    const float* s = W + (size_t)row * Kdim + col;
    short8 v;
#pragma unroll
    for (int j = 0; j < 8; ++j) v[j] = (short)f2bf(s[j]);
    *(short8*)(Wp + (size_t)idx * 8) = v;
}

__global__ void prep_kernel(const float* __restrict__ x,
                            const float* __restrict__ whh0,
                            const float* __restrict__ whh1,
                            const float* __restrict__ wih1,
                            const float* __restrict__ wih0,
                            unsigned short* __restrict__ wsb) {
    int blk = blockIdx.x, tid = threadIdx.x;
    if (blk < 128) {
        pack_w(whh0, wsb + OFS_HH0, 16, blk * 256 + tid);
    } else if (blk < 256) {
        pack_w(whh1, wsb + OFS_HH1, 16, (blk - 128) * 256 + tid);
    } else if (blk < 384) {
        pack_w(wih1, wsb + OFS_IH1, 16, (blk - 256) * 256 + tid);
    } else if (blk < 448) {
        pack_w(wih0, wsb + OFS_IH0, 8, (blk - 384) * 256 + tid);
    } else if (blk < 4544) {
        size_t e = ((size_t)(blk - 448) * 256 + tid) * 8;
        const float* s = x + e;
        short8 v;
#pragma unroll
        for (int j = 0; j < 8; ++j) v[j] = (short)f2bf(s[j]);
        *(short8*)(wsb + OFS_XB + e) = v;
    } else {
        if (tid < 32) ((unsigned int*)((char*)wsb + FLAGS_BYTE))[tid] = 0u;
    }
}

// ---- proj: pre0 = xb @ W_ih0^T + b_ih0 + b_hh0 -> fp32, PACKED for fused --
// fused mapping: blk2 = g*8 + slice, tid2 = w2*64 + lq2*16 + lm2, pv[r2].
// element (t,b,n): g=b>>4, br=b&15, slice=n>>6, w2=(n>>4)&3, lm2=n&15,
//   lq2=br>>2, r2=br&3; idx = ((t*32 + blk2)*256 + tid2)*4 + r2
__global__ __launch_bounds__(512) void proj_kernel(
        const unsigned short* __restrict__ A,
        const unsigned short* __restrict__ Wp,
        const float* __restrict__ bias1, const float* __restrict__ bias2,
        float* __restrict__ out, int KT, int remap) {
    int tid = threadIdx.x, blk = blockIdx.x;
    int w = tid >> 6, l = tid & 63, lm = l & 15, lq = l >> 4;
    int mg = w >> 1, nh = w & 1;
    int Kdim = KT * 32;
    int r0 = blk * 64 + mg * 16;

    floatx4 acc[16];
#pragma unroll
    for (int i = 0; i < 16; ++i) acc[i] = (floatx4)0.f;

    for (int kt = 0; kt < KT; ++kt) {
        short8 a = *(const short8*)(A + (size_t)(r0 + lm) * Kdim + kt * 32 + lq * 8);
#pragma unroll
        for (int i = 0; i < 16; ++i) {
            int ntg = nh * 16 + i;
            short8 b = *(const short8*)(Wp + (((size_t)ntg * KT + kt) * 64 + l) * 8);
            acc[i] = MFMA_BF16(a, b, acc[i]);
        }
    }
#pragma unroll
    for (int i = 0; i < 16; ++i) {
        int n = (nh * 16 + i) * 16 + lm;
        float bs = bias1[n] + bias2[n];
        int slice2 = n >> 6, w2 = (n >> 4) & 3, lm2 = n & 15;
#pragma unroll
        for (int r = 0; r < 4; ++r) {
            int row = r0 + lq * 4 + r;
            int tt, b;
            if (remap) { b = row >> 9; tt = row & 511; }
            else       { tt = row >> 6; b = row & 63; }
            int g2 = b >> 4, br = b & 15;
            int blk2 = g2 * 8 + slice2;
            int tid2 = w2 * 64 + (br >> 2) * 16 + lm2;
            size_t idx = (((size_t)tt * 32 + blk2) * 256 + tid2) * 4 + (br & 3);
            out[idx] = acc[i][r] + bs;
        }
    }
}

// ---- fused 2-layer scan: 32 blocks = 4 groups x 8 slices, 256 threads ----
__global__ __launch_bounds__(256, 1) void fused_kernel(
        const float* __restrict__ pre,           // packed fp32 (layer-0 input proj)
        const unsigned short* __restrict__ Whh0, // packed bf16 KT=16
        const unsigned short* __restrict__ Whh1,
        const unsigned short* __restrict__ Wih1,
        unsigned int* __restrict__ hex,          // merged exchange, u32 col-pairs
        unsigned int* __restrict__ flags,        // [32]
        const float* __restrict__ bih1, const float* __restrict__ bhh1,
        const float* __restrict__ wfc, const float* __restrict__ bfc,
        float* __restrict__ out) {
    __shared__ unsigned short h0[2][16][512];       // 32 KB, XOR-swizzled chunks
    __shared__ unsigned short h1[2][16][512];       // 32 KB

    const int tid = threadIdx.x;
    const int w = tid >> 6, l = tid & 63, lm = l & 15, lq = l >> 4;
    const int blk = blockIdx.x, g = blk >> 3, slice = blk & 7;
    const int ntg = slice * 4 + w;            // global 16-col tile (0..31)
    const int ncol = ntg * 16 + lm;           // global col this thread produces
    const int s2 = slice * 2;                 // own k-tiles {s2, s2+1}

    // zero all h state (t<0 states and partner regions)
    {
        uintx4* z0 = (uintx4*)&h0[0][0][0];
        uintx4* z1 = (uintx4*)&h1[0][0][0];
        for (int i = tid; i < 1024; i += 256) { z0[i] = (uintx4)0u; z1[i] = (uintx4)0u; }
    }
    // Weights register-resident, PRE-ROTATED: breg?[j] = k-tile (s2+j)&15.
    // 48 short8 = 192 VGPR; cap at (256,1) is 512 -> ample headroom.
    short8 breg0[16], bregI[16], breg1[16];
#pragma unroll
    for (int j = 0; j < 16; ++j) {
        int kt = (s2 + j) & 15;
        size_t src = (((size_t)ntg * 16 + kt) * 64 + l) * 8;
        breg0[j] = *(const short8*)(Whh0 + src);
        bregI[j] = *(const short8*)(Wih1 + src);
        breg1[j] = *(const short8*)(Whh1 + src);
    }
    const float b1v = bih1[ncol] + bhh1[ncol];
    __syncthreads();

    // exchange-phase constants: thread t covers chunk c = t&63 (8 cols) at
    // rows r_j = j*4 + (t>>6), j=0..3  (per layer, per iter)
    const int cch = tid & 63;                      // logical chunk
    const int rbase = tid >> 6;                    // row offset within quad
    const bool dl = (cch >> 3) != slice;           // partner chunks only
    const bool poller = (w == 1) && (l < 7);
    const int ps = (slice + 1 + l) & 7;            // partner slice for lanes 0..6
    const int mychunk = ncol >> 3;

    for (int i = 0; i <= 512; ++i) {
        const int sl = i & 1, slw = sl ^ 1;

        // --- A: wave-1 lanes 0-6 poll all 7 partner flags in parallel ---
        if (poller && i >= 1) {
            unsigned int tgt = (unsigned int)i;
            while (__hip_atomic_load(&flags[g * 8 + ps],
                                     __ATOMIC_ACQUIRE, __HIP_MEMORY_SCOPE_AGENT) < tgt)
                __builtin_amdgcn_s_sleep(2);
        }
        __syncthreads();

        // --- B: issue partner loads (both layers) + pre ---
        const bool ld0 = dl && (i >= 1);
        const bool ld1 = dl && (i >= 2);
        uintx4 v0[4], v1[4];
        if (ld0) {
            const uintx4* s = (const uintx4*)(hex + (size_t)((sl * 4 + g) * 2 + 0) * 4096);
#pragma unroll
            for (int j = 0; j < 4; ++j) v0[j] = s[j * 256 + tid];
        }
        if (ld1) {
            const uintx4* s = (const uintx4*)(hex + (size_t)((sl * 4 + g) * 2 + 1) * 4096);
#pragma unroll
            for (int j = 0; j < 4; ++j) v1[j] = s[j * 256 + tid];
        }
        floatx4 pv = (floatx4)0.f;
        if (i <= 511)
            pv = *(const floatx4*)(pre + (((size_t)i * 32 + blk) * 256 + tid) * 4);

        // --- early: own k-tiles j=0..1 (own cols already in LDS slot sl) ---
        floatx4 acc0 = (floatx4)0.f, acc1 = (floatx4)0.f;
#pragma unroll
        for (int j = 0; j < 2; ++j) {
            int kt = s2 + j;
            int ch = ((kt * 4 + lq) ^ (lm & 7)) << 3;
            short8 a = *(const short8*)&h0[sl][lm][ch];
            acc0 = MFMA_BF16(a, breg0[j], acc0);
            acc1 = MFMA_BF16(a, bregI[j], acc1);
            short8 a1 = *(const short8*)&h1[sl][lm][ch];
            acc1 = MFMA_BF16(a1, breg1[j], acc1);
        }

        // --- D: commit partner data (chunks c, rows j*4+rbase, swizzled) ---
        if (ld0) {
#pragma unroll
            for (int j = 0; j < 4; ++j) {
                int r = j * 4 + rbase;
                *(uintx4*)&h0[sl][r][(cch ^ (r & 7)) * 8] = v0[j];
            }
        }
        if (ld1) {
#pragma unroll
            for (int j = 0; j < 4; ++j) {
                int r = j * 4 + rbase;
                *(uintx4*)&h1[sl][r][(cch ^ (r & 7)) * 8] = v1[j];
            }
        }
        __syncthreads();

        // --- main: k-tiles j=2..15 (literal breg indices) ---
#pragma unroll
        for (int j = 2; j < 16; ++j) {
            int kt = (s2 + j) & 15;                // runtime only in LDS address
            int ch = ((kt * 4 + lq) ^ (lm & 7)) << 3;
            short8 a = *(const short8*)&h0[sl][lm][ch];
            acc0 = MFMA_BF16(a, breg0[j], acc0);
            acc1 = MFMA_BF16(a, bregI[j], acc1);
            short8 a1 = *(const short8*)&h1[sl][lm][ch];
            acc1 = MFMA_BF16(a1, breg1[j], acc1);
        }

        // --- E: layer-0 step i -> h0_{i+1} ---
        if (i <= 511) {
            unsigned int* exw = hex + (size_t)((slw * 4 + g) * 2 + 0) * 4096;
#pragma unroll
            for (int r = 0; r < 4; ++r) {
                int row = lq * 4 + r;
                unsigned int hb = f2bf(fast_tanh(acc0[r] + pv[r]));
                unsigned int pk = hb | ((unsigned int)__shfl_xor((int)hb, 1) << 16);
                if (!(lm & 1)) {
                    *(unsigned int*)&h0[slw][row][((mychunk ^ (row & 7)) << 3) | (ncol & 7)] = pk;
                    exw[(size_t)row * 256 + (ncol >> 1)] = pk;
                }
            }
        }

        // --- F: layer-1 step i-1 -> h1_{i-1} ---
        if (i >= 1) {
            unsigned int* exw = hex + (size_t)((slw * 4 + g) * 2 + 1) * 4096;
#pragma unroll
            for (int r = 0; r < 4; ++r) {
                int row = lq * 4 + r;
                unsigned int hb = f2bf(fast_tanh(acc1[r] + b1v));
                unsigned int pk = hb | ((unsigned int)__shfl_xor((int)hb, 1) << 16);
                if (!(lm & 1)) {
                    *(unsigned int*)&h1[slw][row][((mychunk ^ (row & 7)) << 3) | (ncol & 7)] = pk;
                    exw[(size_t)row * 256 + (ncol >> 1)] = pk;
                }
            }
        }

        __syncthreads();   // drains vmcnt before release post

        // --- G: single post covering both layers ---
        if (tid == 0)
            __hip_atomic_fetch_add(&flags[blk], 1u,
                                   __ATOMIC_RELEASE, __HIP_MEMORY_SCOPE_AGENT);
    }

    // --- FC head: slice-0 blocks gather full h1_511 and reduce ---
    if (slice == 0) {
        if (poller) {   // final post value is 513
            while (__hip_atomic_load(&flags[g * 8 + ps],
                                     __ATOMIC_ACQUIRE, __HIP_MEMORY_SCOPE_AGENT) < 513u)
                __builtin_amdgcn_s_sleep(2);
        }
        __syncthreads();
        if (dl) {    // h1_511 lives in hex slot 1, layer 1
            const uintx4* s = (const uintx4*)(hex + (size_t)((1 * 4 + g) * 2 + 1) * 4096);
#pragma unroll
            for (int j = 0; j < 4; ++j) {
                uintx4 v = s[j * 256 + tid];
                int r = j * 4 + rbase;
                *(uintx4*)&h1[1][r][(cch ^ (r & 7)) * 8] = v;
            }
        }
        __syncthreads();
        if (tid < 160) {
            int b = tid / 10, c = tid % 10;
            float s = bfc[c];
            for (int n = 0; n < 512; ++n) {
                unsigned short hb = h1[1][b][(((n >> 3) ^ (b & 7)) << 3) | (n & 7)];
                s += bf2f(hb) * wfc[c * 512 + n];
            }
            out[(size_t)(g * 16 + b) * 10 + c] = s;
        }
    }
}

extern "C" void kernel_launch(void* const* d_in, const int* in_sizes, int n_in,
                              void* d_out, int out_size, void* d_ws, size_t ws_size,
                              hipStream_t stream) {
    const float* x    = (const float*)d_in[0];
    const float* wih0 = (const float*)d_in[1];
    const float* whh0 = (const float*)d_in[2];
    const float* bih0 = (const float*)d_in[3];
    const float* bhh0 = (const float*)d_in[4];
    const float* wih1 = (const float*)d_in[5];
    const float* whh1 = (const float*)d_in[6];
    const float* bih1 = (const float*)d_in[7];
    const float* bhh1 = (const float*)d_in[8];
    const float* wfc  = (const float*)d_in[9];
    const float* bfc  = (const float*)d_in[10];
    float* out = (float*)d_out;

    unsigned short* wsb  = (unsigned short*)d_ws;
    unsigned short* xb   = wsb + OFS_XB;
    unsigned int* hex    = (unsigned int*)((char*)d_ws + HEX_BYTE);
    unsigned int* flags  = (unsigned int*)((char*)d_ws + FLAGS_BYTE);
    float* pre = (float*)((char*)d_ws + PRE_B);

    // 1. pack weights + convert x + zero flags
    prep_kernel<<<dim3(4545), dim3(256), 0, stream>>>(x, whh0, whh1, wih1, wih0, wsb);
    // 2. pre0 = x @ w_ih0^T + b_ih0 + b_hh0  (packed for fused kernel)
    proj_kernel<<<dim3(512), dim3(512), 0, stream>>>(xb, wsb + OFS_IH0, bih0, bhh0, pre, 8, 1);
    // 3. fused 2-layer scan + FC head
    fused_kernel<<<dim3(32), dim3(256), 0, stream>>>(
        pre, wsb + OFS_HH0, wsb + OFS_HH1, wsb + OFS_IH1,
        hex, flags, bih1, bhh1, wfc, bfc, out);
}

// Round 10
// 2521.413 us; speedup vs baseline: 2.8124x; 1.1967x over previous
//
#include <hip/hip_runtime.h>
#include <hip/hip_bf16.h>
#include <math.h>

// ---------------------------------------------------------------------------
// 2-layer tanh RNN, B=64 S=512 I=256 H=512, fp32 in/out, bf16 MFMA compute.
// Round 10: R8 base (proven 2977 us, absmax 1.95e-3) + XCD-LOCAL EXCHANGE.
// R8 put the 8 cooperating col-slices of each batch-group on 8 DIFFERENT
// XCDs (blockIdx%8 = XCD round-robin), so every per-step flag/hex round
// trip crossed the Infinity Fabric. Here: physical block blk is active iff
// (blk&7)<4; g = blk&7, slice = blk>>3  =>  all 8 slices of group g sit on
// XCD g, exchange served by the shared per-XCD L2 (~200-300 cy) instead of
// L3/IF (~1-2k cy). Plus: flag release-STORE (no RMW) and no-sleep polls.
// R9 lesson (reverted): 1024-thr blocks cap at 128 regs/wave, and full
// 3-matrix residency (1.5 MB) exceeds a CU's 512 KB RF -- col-split is
// forced by capacity; weight re-streaming via L2/L3 is measured-harmless.
//
// Lag-1 pipeline per iter i (0..512): L0 step i (i<=511), L1 step i-1 (i>=1)
//   A: wave1 lanes0-6 poll 7 partner flags >= i; barrier
//   B: issue partner hex loads (all non-own chunks, both layers) + pre_i
//   early: own k-tiles j=0..1 (own cols already in LDS from prev iter)
//   D: commit partner data to LDS slot i&1; barrier
//   main: k-tiles j=2..15
//   E: h0_{i+1}=tanh(acc0+pre) -> LDS slot (i+1)&1 + hex slot (i+1)&1
//   F: h1_{i-1}=tanh(acc1+b1)  -> LDS slot (i+1)&1 + hex slot (i+1)&1
//   G: barrier (drains stores); wave0 lane0 release-stores flags[lblk]=i+1
//
// ws layout (bytes):
//   [0)        Wp_hh0  bf16 packed  512 KB
//   [524288)   Wp_hh1  bf16 packed  512 KB
//   [1048576)  Wp_ih1  bf16 packed  512 KB
//   [1572864)  Wp_ih0  bf16 packed  256 KB
//   [1835008)  hex     2 slots x 4 g x 2 layers x 16 x 256 u32 = 256 KB
//   [2097152)  xb      bf16 [32768][256]  16 MB
//   [18874368) flags   [32] u32
//   [52428800) pre     fp32 PACKED ((t*32+lblk)*256+tid)*4+r   64 MB
// ---------------------------------------------------------------------------

typedef __attribute__((ext_vector_type(8))) short  short8;
typedef __attribute__((ext_vector_type(4))) float  floatx4;
typedef __attribute__((ext_vector_type(4))) unsigned int uintx4;

#define MFMA_BF16(a, b, c) __builtin_amdgcn_mfma_f32_16x16x32_bf16((a), (b), (c), 0, 0, 0)

// offsets in u16 units for bf16 regions
#define OFS_HH0   ((size_t)0)
#define OFS_HH1   ((size_t)262144)
#define OFS_IH1   ((size_t)524288)
#define OFS_IH0   ((size_t)786432)
#define OFS_XB    ((size_t)1048576)
#define HEX_BYTE   ((size_t)1835008)
#define FLAGS_BYTE ((size_t)18874368)
#define PRE_B      ((size_t)52428800)

__device__ __forceinline__ unsigned short f2bf(float f) {
    unsigned u = __builtin_bit_cast(unsigned, f);
    u += 0x7fffu + ((u >> 16) & 1u);          // round-to-nearest-even
    return (unsigned short)(u >> 16);
}
__device__ __forceinline__ float bf2f(unsigned short h) {
    return __builtin_bit_cast(float, ((unsigned)h) << 16);
}
__device__ __forceinline__ float fast_tanh(float x) {
    float z = fminf(9.0f, fmaxf(-9.0f, x));
    float e = __builtin_amdgcn_exp2f(z * 2.88539008f);   // e^{2z}
    return (e - 1.0f) * __builtin_amdgcn_rcpf(e + 1.0f);
}

// ---- prep: pack weights into MFMA B-fragment order + convert x + flags ----
__device__ __forceinline__ void pack_w(const float* __restrict__ W,
                                       unsigned short* __restrict__ Wp,
                                       int KT, int idx) {
    int l  = idx & 63;
    int kt = (idx >> 6) % KT;
    int nt = (idx >> 6) / KT;
    int Kdim = KT * 32;
    int row = nt * 16 + (l & 15);
    int col = kt * 32 + (l >> 4) * 8;
    const float* s = W + (size_t)row * Kdim + col;
    short8 v;
#pragma unroll
    for (int j = 0; j < 8; ++j) v[j] = (short)f2bf(s[j]);
    *(short8*)(Wp + (size_t)idx * 8) = v;
}

__global__ void prep_kernel(const float* __restrict__ x,
                            const float* __restrict__ whh0,
                            const float* __restrict__ whh1,
                            const float* __restrict__ wih1,
                            const float* __restrict__ wih0,
                            unsigned short* __restrict__ wsb) {
    int blk = blockIdx.x, tid = threadIdx.x;
    if (blk < 128) {
        pack_w(whh0, wsb + OFS_HH0, 16, blk * 256 + tid);
    } else if (blk < 256) {
        pack_w(whh1, wsb + OFS_HH1, 16, (blk - 128) * 256 + tid);
    } else if (blk < 384) {
        pack_w(wih1, wsb + OFS_IH1, 16, (blk - 256) * 256 + tid);
    } else if (blk < 448) {
        pack_w(wih0, wsb + OFS_IH0, 8, (blk - 384) * 256 + tid);
    } else if (blk < 4544) {
        size_t e = ((size_t)(blk - 448) * 256 + tid) * 8;
        const float* s = x + e;
        short8 v;
#pragma unroll
        for (int j = 0; j < 8; ++j) v[j] = (short)f2bf(s[j]);
        *(short8*)(wsb + OFS_XB + e) = v;
    } else {
        if (tid < 32) ((unsigned int*)((char*)wsb + FLAGS_BYTE))[tid] = 0u;
    }
}

// ---- proj: pre0 = xb @ W_ih0^T + b_ih0 + b_hh0 -> fp32, PACKED for fused --
// fused mapping (logical block lblk = g*8 + slice):
// element (t,b,n): g=b>>4, br=b&15, slice=n>>6, w2=(n>>4)&3, lm2=n&15,
//   lq2=br>>2, r2=br&3; idx = ((t*32 + lblk)*256 + tid2)*4 + r2
__global__ __launch_bounds__(512) void proj_kernel(
        const unsigned short* __restrict__ A,
        const unsigned short* __restrict__ Wp,
        const float* __restrict__ bias1, const float* __restrict__ bias2,
        float* __restrict__ out, int KT) {
    int tid = threadIdx.x, blk = blockIdx.x;
    int w = tid >> 6, l = tid & 63, lm = l & 15, lq = l >> 4;
    int mg = w >> 1, nh = w & 1;
    int Kdim = KT * 32;
    int r0 = blk * 64 + mg * 16;

    floatx4 acc[16];
#pragma unroll
    for (int i = 0; i < 16; ++i) acc[i] = (floatx4)0.f;

    for (int kt = 0; kt < KT; ++kt) {
        short8 a = *(const short8*)(A + (size_t)(r0 + lm) * Kdim + kt * 32 + lq * 8);
#pragma unroll
        for (int i = 0; i < 16; ++i) {
            int ntg = nh * 16 + i;
            short8 b = *(const short8*)(Wp + (((size_t)ntg * KT + kt) * 64 + l) * 8);
            acc[i] = MFMA_BF16(a, b, acc[i]);
        }
    }
#pragma unroll
    for (int i = 0; i < 16; ++i) {
        int n = (nh * 16 + i) * 16 + lm;
        float bs = bias1[n] + bias2[n];
        int slice2 = n >> 6, w2 = (n >> 4) & 3, lm2 = n & 15;
#pragma unroll
        for (int r = 0; r < 4; ++r) {
            int row = r0 + lq * 4 + r;                  // row = b*512 + t
            int b = row >> 9, tt = row & 511;
            int g2 = b >> 4, br = b & 15;
            int lblk2 = g2 * 8 + slice2;
            int tid2 = w2 * 64 + (br >> 2) * 16 + lm2;
            size_t idx = (((size_t)tt * 32 + lblk2) * 256 + tid2) * 4 + (br & 3);
            out[idx] = acc[i][r] + bs;
        }
    }
}

// ---- fused 2-layer scan: 32 active blocks = 4 groups x 8 slices ----------
// Physical grid 60; active iff (blk&7)<4. XCD = blk%8 (round-robin, m09)
// => g = blk&7, slice = blk>>3 puts all 8 slices of group g on XCD g.
__global__ __launch_bounds__(256, 1) void fused_kernel(
        const float* __restrict__ pre,           // packed fp32 (layer-0 input proj)
        const unsigned short* __restrict__ Whh0, // packed bf16 KT=16
        const unsigned short* __restrict__ Whh1,
        const unsigned short* __restrict__ Wih1,
        unsigned int* __restrict__ hex,          // merged exchange, u32 col-pairs
        unsigned int* __restrict__ flags,        // [32]
        const float* __restrict__ bih1, const float* __restrict__ bhh1,
        const float* __restrict__ wfc, const float* __restrict__ bfc,
        float* __restrict__ out) {
    const int pblk = blockIdx.x;
    if ((pblk & 7) >= 4) return;                 // 28 dead residues exit at once

    __shared__ unsigned short h0[2][16][512];       // 32 KB, XOR-swizzled chunks
    __shared__ unsigned short h1[2][16][512];       // 32 KB

    const int tid = threadIdx.x;
    const int w = tid >> 6, l = tid & 63, lm = l & 15, lq = l >> 4;
    const int g = pblk & 7, slice = pblk >> 3;     // XCD-local: XCD(blk)=blk%8=g
    const int lblk = g * 8 + slice;                // logical id for pre/flags
    const int ntg = slice * 4 + w;            // global 16-col tile (0..31)
    const int ncol = ntg * 16 + lm;           // global col this thread produces
    const int s2 = slice * 2;                 // own k-tiles {s2, s2+1}

    // zero all h state (t<0 states and partner regions)
    {
        uintx4* z0 = (uintx4*)&h0[0][0][0];
        uintx4* z1 = (uintx4*)&h1[0][0][0];
        for (int i = tid; i < 1024; i += 256) { z0[i] = (uintx4)0u; z1[i] = (uintx4)0u; }
    }
    // Weights, PRE-ROTATED: breg?[j] = k-tile (s2+j)&15 (literal indices).
    short8 breg0[16], bregI[16], breg1[16];
#pragma unroll
    for (int j = 0; j < 16; ++j) {
        int kt = (s2 + j) & 15;
        size_t src = (((size_t)ntg * 16 + kt) * 64 + l) * 8;
        breg0[j] = *(const short8*)(Whh0 + src);
        bregI[j] = *(const short8*)(Wih1 + src);
        breg1[j] = *(const short8*)(Whh1 + src);
    }
    const float b1v = bih1[ncol] + bhh1[ncol];
    __syncthreads();

    // exchange-phase constants: thread t covers chunk c = t&63 (8 cols) at
    // rows r_j = j*4 + (t>>6), j=0..3  (per layer, per iter)
    const int cch = tid & 63;                      // logical chunk
    const int rbase = tid >> 6;                    // row offset within quad
    const bool dl = (cch >> 3) != slice;           // partner chunks only
    const bool poller = (w == 1) && (l < 7);
    const int ps = (slice + 1 + l) & 7;            // partner slice for lanes 0..6
    const int mychunk = ncol >> 3;

    for (int i = 0; i <= 512; ++i) {
        const int sl = i & 1, slw = sl ^ 1;

        // --- A: wave-1 lanes 0-6 poll all 7 partner flags (no sleep) ---
        if (poller && i >= 1) {
            unsigned int tgt = (unsigned int)i;
            while (__hip_atomic_load(&flags[g * 8 + ps],
                                     __ATOMIC_ACQUIRE, __HIP_MEMORY_SCOPE_AGENT) < tgt)
                ;
        }
        __syncthreads();

        // --- B: issue partner loads (both layers) + pre ---
        const bool ld0 = dl && (i >= 1);
        const bool ld1 = dl && (i >= 2);
        uintx4 v0[4], v1[4];
        if (ld0) {
            const uintx4* s = (const uintx4*)(hex + (size_t)((sl * 4 + g) * 2 + 0) * 4096);
#pragma unroll
            for (int j = 0; j < 4; ++j) v0[j] = s[j * 256 + tid];
        }
        if (ld1) {
            const uintx4* s = (const uintx4*)(hex + (size_t)((sl * 4 + g) * 2 + 1) * 4096);
#pragma unroll
            for (int j = 0; j < 4; ++j) v1[j] = s[j * 256 + tid];
        }
        floatx4 pv = (floatx4)0.f;
        if (i <= 511)
            pv = *(const floatx4*)(pre + (((size_t)i * 32 + lblk) * 256 + tid) * 4);

        // --- early: own k-tiles j=0..1 (own cols already in LDS slot sl) ---
        floatx4 acc0 = (floatx4)0.f, acc1 = (floatx4)0.f;
#pragma unroll
        for (int j = 0; j < 2; ++j) {
            int kt = s2 + j;
            int ch = ((kt * 4 + lq) ^ (lm & 7)) << 3;
            short8 a = *(const short8*)&h0[sl][lm][ch];
            acc0 = MFMA_BF16(a, breg0[j], acc0);
            acc1 = MFMA_BF16(a, bregI[j], acc1);
            short8 a1 = *(const short8*)&h1[sl][lm][ch];
            acc1 = MFMA_BF16(a1, breg1[j], acc1);
        }

        // --- D: commit partner data (chunks c, rows j*4+rbase, swizzled) ---
        if (ld0) {
#pragma unroll
            for (int j = 0; j < 4; ++j) {
                int r = j * 4 + rbase;
                *(uintx4*)&h0[sl][r][(cch ^ (r & 7)) * 8] = v0[j];
            }
        }
        if (ld1) {
#pragma unroll
            for (int j = 0; j < 4; ++j) {
                int r = j * 4 + rbase;
                *(uintx4*)&h1[sl][r][(cch ^ (r & 7)) * 8] = v1[j];
            }
        }
        __syncthreads();

        // --- main: k-tiles j=2..15 (literal breg indices) ---
#pragma unroll
        for (int j = 2; j < 16; ++j) {
            int kt = (s2 + j) & 15;                // runtime only in LDS address
            int ch = ((kt * 4 + lq) ^ (lm & 7)) << 3;
            short8 a = *(const short8*)&h0[sl][lm][ch];
            acc0 = MFMA_BF16(a, breg0[j], acc0);
            acc1 = MFMA_BF16(a, bregI[j], acc1);
            short8 a1 = *(const short8*)&h1[sl][lm][ch];
            acc1 = MFMA_BF16(a1, breg1[j], acc1);
        }

        // --- E: layer-0 step i -> h0_{i+1} ---
        if (i <= 511) {
            unsigned int* exw = hex + (size_t)((slw * 4 + g) * 2 + 0) * 4096;
#pragma unroll
            for (int r = 0; r < 4; ++r) {
                int row = lq * 4 + r;
                unsigned int hb = f2bf(fast_tanh(acc0[r] + pv[r]));
                unsigned int pk = hb | ((unsigned int)__shfl_xor((int)hb, 1) << 16);
                if (!(lm & 1)) {
                    *(unsigned int*)&h0[slw][row][((mychunk ^ (row & 7)) << 3) | (ncol & 7)] = pk;
                    exw[(size_t)row * 256 + (ncol >> 1)] = pk;
                }
            }
        }

        // --- F: layer-1 step i-1 -> h1_{i-1} ---
        if (i >= 1) {
            unsigned int* exw = hex + (size_t)((slw * 4 + g) * 2 + 1) * 4096;
#pragma unroll
            for (int r = 0; r < 4; ++r) {
                int row = lq * 4 + r;
                unsigned int hb = f2bf(fast_tanh(acc1[r] + b1v));
                unsigned int pk = hb | ((unsigned int)__shfl_xor((int)hb, 1) << 16);
                if (!(lm & 1)) {
                    *(unsigned int*)&h1[slw][row][((mychunk ^ (row & 7)) << 3) | (ncol & 7)] = pk;
                    exw[(size_t)row * 256 + (ncol >> 1)] = pk;
                }
            }
        }

        __syncthreads();   // drains vmcnt (all waves) before release post

        // --- G: single release-STORE post (monotonic, single writer) ---
        if (tid == 0)
            __hip_atomic_store(&flags[lblk], (unsigned int)(i + 1),
                               __ATOMIC_RELEASE, __HIP_MEMORY_SCOPE_AGENT);
    }

    // --- FC head: slice-0 blocks gather full h1_511 and reduce ---
    if (slice == 0) {
        if (poller) {   // final post value is 513
            while (__hip_atomic_load(&flags[g * 8 + ps],
                                     __ATOMIC_ACQUIRE, __HIP_MEMORY_SCOPE_AGENT) < 513u)
                ;
        }
        __syncthreads();
        if (dl) {    // h1_511 lives in hex slot 1, layer 1
            const uintx4* s = (const uintx4*)(hex + (size_t)((1 * 4 + g) * 2 + 1) * 4096);
#pragma unroll
            for (int j = 0; j < 4; ++j) {
                uintx4 v = s[j * 256 + tid];
                int r = j * 4 + rbase;
                *(uintx4*)&h1[1][r][(cch ^ (r & 7)) * 8] = v;
            }
        }
        __syncthreads();
        if (tid < 160) {
            int b = tid / 10, c = tid % 10;
            float s = bfc[c];
            for (int n = 0; n < 512; ++n) {
                unsigned short hb = h1[1][b][(((n >> 3) ^ (b & 7)) << 3) | (n & 7)];
                s += bf2f(hb) * wfc[c * 512 + n];
            }
            out[(size_t)(g * 16 + b) * 10 + c] = s;
        }
    }
}

extern "C" void kernel_launch(void* const* d_in, const int* in_sizes, int n_in,
                              void* d_out, int out_size, void* d_ws, size_t ws_size,
                              hipStream_t stream) {
    const float* x    = (const float*)d_in[0];
    const float* wih0 = (const float*)d_in[1];
    const float* whh0 = (const float*)d_in[2];
    const float* bih0 = (const float*)d_in[3];
    const float* bhh0 = (const float*)d_in[4];
    const float* wih1 = (const float*)d_in[5];
    const float* whh1 = (const float*)d_in[6];
    const float* bih1 = (const float*)d_in[7];
    const float* bhh1 = (const float*)d_in[8];
    const float* wfc  = (const float*)d_in[9];
    const float* bfc  = (const float*)d_in[10];
    float* out = (float*)d_out;

    unsigned short* wsb  = (unsigned short*)d_ws;
    unsigned short* xb   = wsb + OFS_XB;
    unsigned int* hex    = (unsigned int*)((char*)d_ws + HEX_BYTE);
    unsigned int* flags  = (unsigned int*)((char*)d_ws + FLAGS_BYTE);
    float* pre = (float*)((char*)d_ws + PRE_B);

    // 1. pack weights + convert x + zero flags
    prep_kernel<<<dim3(4545), dim3(256), 0, stream>>>(x, whh0, whh1, wih1, wih0, wsb);
    // 2. pre0 = x @ w_ih0^T + b_ih0 + b_hh0  (packed for fused kernel)
    proj_kernel<<<dim3(512), dim3(512), 0, stream>>>(xb, wsb + OFS_IH0, bih0, bhh0, pre, 8);
    // 3. fused 2-layer scan + FC head (grid 60: 32 active, XCD-local groups)
    fused_kernel<<<dim3(60), dim3(256), 0, stream>>>(
        pre, wsb + OFS_HH0, wsb + OFS_HH1, wsb + OFS_IH1,
        hex, flags, bih1, bhh1, wfc, bfc, out);
}

// Round 11
// 2390.489 us; speedup vs baseline: 2.9664x; 1.0548x over previous
//
#include <hip/hip_runtime.h>
#include <hip/hip_bf16.h>
#include <math.h>

// ---------------------------------------------------------------------------
// 2-layer tanh RNN, B=64 S=512 I=256 H=512, fp32 in/out, bf16 MFMA compute.
// Round 11: R10 base (proven 2521 us, absmax 1.95e-3, XCD-local exchange)
// + AGPR-RESIDENT WEIGHTS. R10's VGPR_Count=152 showed the 48 weight frags
// were still sunk to per-iter L2 re-streams (3 x 128 KB/iter ~ 6k cy of the
// 11.5k cy/iter). Fix: pin each fragment into the AGPR file with a no-op
// asm ("+a") right after the load. The asm output is not rematerializable,
// so the R6-R8 "sink the load back into the loop" escape hatch is closed;
// at 256 thr/block + __launch_bounds__(256,1) the unified budget is 512
// regs/wave, and 192 AGPR + ~150 VGPR fits with slack (R9's failure was
// 1024-thr geometry = 128-reg cap -> scratch spills, plus unordered s_nop
// hazards; here ALL real instructions stay compiler-generated and gfx950
// MFMA reads B directly from AGPR - no copies, no manual hazards).
//
// 32 active blocks = 4 groups x 8 slices, all 8 slices of group g on XCD g
// (physical blk: active iff (blk&7)<4; g=blk&7, slice=blk>>3; grid 60).
// Lag-1 pipeline per iter i (0..512): L0 step i (i<=511), L1 step i-1 (i>=1)
//   A: wave1 lanes0-6 poll 7 partner flags >= i (no sleep); barrier
//   B: issue partner hex loads (both layers) + pre_i
//   early: own k-tiles j=0..1
//   D: commit partner data to LDS slot i&1; barrier
//   main: k-tiles j=2..15
//   E: h0_{i+1}=tanh(acc0+pre) -> LDS slot (i+1)&1 + hex slot (i+1)&1
//   F: h1_{i-1}=tanh(acc1+b1)  -> LDS slot (i+1)&1 + hex slot (i+1)&1
//   G: barrier (drains all waves' vmcnt); wave0 release-stores flags=i+1
//
// ws layout (bytes):
//   [0)        Wp_hh0  bf16 packed  512 KB
//   [524288)   Wp_hh1  bf16 packed  512 KB
//   [1048576)  Wp_ih1  bf16 packed  512 KB
//   [1572864)  Wp_ih0  bf16 packed  256 KB
//   [1835008)  hex     2 slots x 4 g x 2 layers x 16 x 256 u32 = 256 KB
//   [2097152)  xb      bf16 [32768][256]  16 MB
//   [18874368) flags   [32] u32
//   [52428800) pre     fp32 PACKED ((t*32+lblk)*256+tid)*4+r   64 MB
// ---------------------------------------------------------------------------

typedef __attribute__((ext_vector_type(8))) short  short8;
typedef __attribute__((ext_vector_type(4))) float  floatx4;
typedef __attribute__((ext_vector_type(4))) unsigned int uintx4;

#define MFMA_BF16(a, b, c) __builtin_amdgcn_mfma_f32_16x16x32_bf16((a), (b), (c), 0, 0, 0)

// offsets in u16 units for bf16 regions
#define OFS_HH0   ((size_t)0)
#define OFS_HH1   ((size_t)262144)
#define OFS_IH1   ((size_t)524288)
#define OFS_IH0   ((size_t)786432)
#define OFS_XB    ((size_t)1048576)
#define HEX_BYTE   ((size_t)1835008)
#define FLAGS_BYTE ((size_t)18874368)
#define PRE_B      ((size_t)52428800)

__device__ __forceinline__ unsigned short f2bf(float f) {
    unsigned u = __builtin_bit_cast(unsigned, f);
    u += 0x7fffu + ((u >> 16) & 1u);          // round-to-nearest-even
    return (unsigned short)(u >> 16);
}
__device__ __forceinline__ float bf2f(unsigned short h) {
    return __builtin_bit_cast(float, ((unsigned)h) << 16);
}
__device__ __forceinline__ float fast_tanh(float x) {
    float z = fminf(9.0f, fmaxf(-9.0f, x));
    float e = __builtin_amdgcn_exp2f(z * 2.88539008f);   // e^{2z}
    return (e - 1.0f) * __builtin_amdgcn_rcpf(e + 1.0f);
}

// ---- prep: pack weights into MFMA B-fragment order + convert x + flags ----
__device__ __forceinline__ void pack_w(const float* __restrict__ W,
                                       unsigned short* __restrict__ Wp,
                                       int KT, int idx) {
    int l  = idx & 63;
    int kt = (idx >> 6) % KT;
    int nt = (idx >> 6) / KT;
    int Kdim = KT * 32;
    int row = nt * 16 + (l & 15);
    int col = kt * 32 + (l >> 4) * 8;
    const float* s = W + (size_t)row * Kdim + col;
    short8 v;
#pragma unroll
    for (int j = 0; j < 8; ++j) v[j] = (short)f2bf(s[j]);
    *(short8*)(Wp + (size_t)idx * 8) = v;
}

__global__ void prep_kernel(const float* __restrict__ x,
                            const float* __restrict__ whh0,
                            const float* __restrict__ whh1,
                            const float* __restrict__ wih1,
                            const float* __restrict__ wih0,
                            unsigned short* __restrict__ wsb) {
    int blk = blockIdx.x, tid = threadIdx.x;
    if (blk < 128) {
        pack_w(whh0, wsb + OFS_HH0, 16, blk * 256 + tid);
    } else if (blk < 256) {
        pack_w(whh1, wsb + OFS_HH1, 16, (blk - 128) * 256 + tid);
    } else if (blk < 384) {
        pack_w(wih1, wsb + OFS_IH1, 16, (blk - 256) * 256 + tid);
    } else if (blk < 448) {
        pack_w(wih0, wsb + OFS_IH0, 8, (blk - 384) * 256 + tid);
    } else if (blk < 4544) {
        size_t e = ((size_t)(blk - 448) * 256 + tid) * 8;
        const float* s = x + e;
        short8 v;
#pragma unroll
        for (int j = 0; j < 8; ++j) v[j] = (short)f2bf(s[j]);
        *(short8*)(wsb + OFS_XB + e) = v;
    } else {
        if (tid < 32) ((unsigned int*)((char*)wsb + FLAGS_BYTE))[tid] = 0u;
    }
}

// ---- proj: pre0 = xb @ W_ih0^T + b_ih0 + b_hh0 -> fp32, PACKED for fused --
// fused mapping (logical block lblk = g*8 + slice):
// element (t,b,n): g=b>>4, br=b&15, slice=n>>6, w2=(n>>4)&3, lm2=n&15,
//   lq2=br>>2, r2=br&3; idx = ((t*32 + lblk)*256 + tid2)*4 + r2
__global__ __launch_bounds__(512) void proj_kernel(
        const unsigned short* __restrict__ A,
        const unsigned short* __restrict__ Wp,
        const float* __restrict__ bias1, const float* __restrict__ bias2,
        float* __restrict__ out, int KT) {
    int tid = threadIdx.x, blk = blockIdx.x;
    int w = tid >> 6, l = tid & 63, lm = l & 15, lq = l >> 4;
    int mg = w >> 1, nh = w & 1;
    int Kdim = KT * 32;
    int r0 = blk * 64 + mg * 16;

    floatx4 acc[16];
#pragma unroll
    for (int i = 0; i < 16; ++i) acc[i] = (floatx4)0.f;

    for (int kt = 0; kt < KT; ++kt) {
        short8 a = *(const short8*)(A + (size_t)(r0 + lm) * Kdim + kt * 32 + lq * 8);
#pragma unroll
        for (int i = 0; i < 16; ++i) {
            int ntg = nh * 16 + i;
            short8 b = *(const short8*)(Wp + (((size_t)ntg * KT + kt) * 64 + l) * 8);
            acc[i] = MFMA_BF16(a, b, acc[i]);
        }
    }
#pragma unroll
    for (int i = 0; i < 16; ++i) {
        int n = (nh * 16 + i) * 16 + lm;
        float bs = bias1[n] + bias2[n];
        int slice2 = n >> 6, w2 = (n >> 4) & 3, lm2 = n & 15;
#pragma unroll
        for (int r = 0; r < 4; ++r) {
            int row = r0 + lq * 4 + r;                  // row = b*512 + t
            int b = row >> 9, tt = row & 511;
            int g2 = b >> 4, br = b & 15;
            int lblk2 = g2 * 8 + slice2;
            int tid2 = w2 * 64 + (br >> 2) * 16 + lm2;
            size_t idx = (((size_t)tt * 32 + lblk2) * 256 + tid2) * 4 + (br & 3);
            out[idx] = acc[i][r] + bs;
        }
    }
}

// ---- fused 2-layer scan: 32 active blocks = 4 groups x 8 slices ----------
// Physical grid 60; active iff (blk&7)<4. XCD = blk%8 (round-robin, m09)
// => g = blk&7, slice = blk>>3 puts all 8 slices of group g on XCD g.
__global__ __launch_bounds__(256, 1) void fused_kernel(
        const float* __restrict__ pre,           // packed fp32 (layer-0 input proj)
        const unsigned short* __restrict__ Whh0, // packed bf16 KT=16
        const unsigned short* __restrict__ Whh1,
        const unsigned short* __restrict__ Wih1,
        unsigned int* __restrict__ hex,          // merged exchange, u32 col-pairs
        unsigned int* __restrict__ flags,        // [32]
        const float* __restrict__ bih1, const float* __restrict__ bhh1,
        const float* __restrict__ wfc, const float* __restrict__ bfc,
        float* __restrict__ out) {
    const int pblk = blockIdx.x;
    if ((pblk & 7) >= 4) return;                 // 28 dead residues exit at once

    __shared__ unsigned short h0[2][16][512];       // 32 KB, XOR-swizzled chunks
    __shared__ unsigned short h1[2][16][512];       // 32 KB

    const int tid = threadIdx.x;
    const int w = tid >> 6, l = tid & 63, lm = l & 15, lq = l >> 4;
    const int g = pblk & 7, slice = pblk >> 3;     // XCD-local: XCD(blk)=blk%8=g
    const int lblk = g * 8 + slice;                // logical id for pre/flags
    const int ntg = slice * 4 + w;            // global 16-col tile (0..31)
    const int ncol = ntg * 16 + lm;           // global col this thread produces
    const int s2 = slice * 2;                 // own k-tiles {s2, s2+1}

    // zero all h state (t<0 states and partner regions)
    {
        uintx4* z0 = (uintx4*)&h0[0][0][0];
        uintx4* z1 = (uintx4*)&h1[0][0][0];
        for (int i = tid; i < 1024; i += 256) { z0[i] = (uintx4)0u; z1[i] = (uintx4)0u; }
    }
    // Weights, PRE-ROTATED: breg?[j] = k-tile (s2+j)&15 (literal indices).
    // AGPR-pin each fragment: the "+a" asm output is not rematerializable,
    // so the compiler cannot sink the load back into the loop (R6-R8 mode).
    // 48 frags x 4 regs = 192 AGPR; +~150 VGPR working set < 512 budget.
    short8 breg0[16], bregI[16], breg1[16];
#pragma unroll
    for (int j = 0; j < 16; ++j) {
        int kt = (s2 + j) & 15;
        size_t src = (((size_t)ntg * 16 + kt) * 64 + l) * 8;
        breg0[j] = *(const short8*)(Whh0 + src);
        bregI[j] = *(const short8*)(Wih1 + src);
        breg1[j] = *(const short8*)(Whh1 + src);
        asm volatile("" : "+a"(breg0[j]), "+a"(bregI[j]), "+a"(breg1[j]));
    }
    const float b1v = bih1[ncol] + bhh1[ncol];
    __syncthreads();

    // exchange-phase constants: thread t covers chunk c = t&63 (8 cols) at
    // rows r_j = j*4 + (t>>6), j=0..3  (per layer, per iter)
    const int cch = tid & 63;                      // logical chunk
    const int rbase = tid >> 6;                    // row offset within quad
    const bool dl = (cch >> 3) != slice;           // partner chunks only
    const bool poller = (w == 1) && (l < 7);
    const int ps = (slice + 1 + l) & 7;            // partner slice for lanes 0..6
    const int mychunk = ncol >> 3;

    for (int i = 0; i <= 512; ++i) {
        const int sl = i & 1, slw = sl ^ 1;

        // --- A: wave-1 lanes 0-6 poll all 7 partner flags (no sleep) ---
        if (poller && i >= 1) {
            unsigned int tgt = (unsigned int)i;
            while (__hip_atomic_load(&flags[g * 8 + ps],
                                     __ATOMIC_ACQUIRE, __HIP_MEMORY_SCOPE_AGENT) < tgt)
                ;
        }
        __syncthreads();

        // --- B: issue partner loads (both layers) + pre ---
        const bool ld0 = dl && (i >= 1);
        const bool ld1 = dl && (i >= 2);
        uintx4 v0[4], v1[4];
        if (ld0) {
            const uintx4* s = (const uintx4*)(hex + (size_t)((sl * 4 + g) * 2 + 0) * 4096);
#pragma unroll
            for (int j = 0; j < 4; ++j) v0[j] = s[j * 256 + tid];
        }
        if (ld1) {
            const uintx4* s = (const uintx4*)(hex + (size_t)((sl * 4 + g) * 2 + 1) * 4096);
#pragma unroll
            for (int j = 0; j < 4; ++j) v1[j] = s[j * 256 + tid];
        }
        floatx4 pv = (floatx4)0.f;
        if (i <= 511)
            pv = *(const floatx4*)(pre + (((size_t)i * 32 + lblk) * 256 + tid) * 4);

        // --- early: own k-tiles j=0..1 (own cols already in LDS slot sl) ---
        floatx4 acc0 = (floatx4)0.f, acc1 = (floatx4)0.f;
#pragma unroll
        for (int j = 0; j < 2; ++j) {
            int kt = s2 + j;
            int ch = ((kt * 4 + lq) ^ (lm & 7)) << 3;
            short8 a = *(const short8*)&h0[sl][lm][ch];
            acc0 = MFMA_BF16(a, breg0[j], acc0);
            acc1 = MFMA_BF16(a, bregI[j], acc1);
            short8 a1 = *(const short8*)&h1[sl][lm][ch];
            acc1 = MFMA_BF16(a1, breg1[j], acc1);
        }

        // --- D: commit partner data (chunks c, rows j*4+rbase, swizzled) ---
        if (ld0) {
#pragma unroll
            for (int j = 0; j < 4; ++j) {
                int r = j * 4 + rbase;
                *(uintx4*)&h0[sl][r][(cch ^ (r & 7)) * 8] = v0[j];
            }
        }
        if (ld1) {
#pragma unroll
            for (int j = 0; j < 4; ++j) {
                int r = j * 4 + rbase;
                *(uintx4*)&h1[sl][r][(cch ^ (r & 7)) * 8] = v1[j];
            }
        }
        __syncthreads();

        // --- main: k-tiles j=2..15 (literal breg indices) ---
#pragma unroll
        for (int j = 2; j < 16; ++j) {
            int kt = (s2 + j) & 15;                // runtime only in LDS address
            int ch = ((kt * 4 + lq) ^ (lm & 7)) << 3;
            short8 a = *(const short8*)&h0[sl][lm][ch];
            acc0 = MFMA_BF16(a, breg0[j], acc0);
            acc1 = MFMA_BF16(a, bregI[j], acc1);
            short8 a1 = *(const short8*)&h1[sl][lm][ch];
            acc1 = MFMA_BF16(a1, breg1[j], acc1);
        }

        // --- E: layer-0 step i -> h0_{i+1} ---
        if (i <= 511) {
            unsigned int* exw = hex + (size_t)((slw * 4 + g) * 2 + 0) * 4096;
#pragma unroll
            for (int r = 0; r < 4; ++r) {
                int row = lq * 4 + r;
                unsigned int hb = f2bf(fast_tanh(acc0[r] + pv[r]));
                unsigned int pk = hb | ((unsigned int)__shfl_xor((int)hb, 1) << 16);
                if (!(lm & 1)) {
                    *(unsigned int*)&h0[slw][row][((mychunk ^ (row & 7)) << 3) | (ncol & 7)] = pk;
                    exw[(size_t)row * 256 + (ncol >> 1)] = pk;
                }
            }
        }

        // --- F: layer-1 step i-1 -> h1_{i-1} ---
        if (i >= 1) {
            unsigned int* exw = hex + (size_t)((slw * 4 + g) * 2 + 1) * 4096;
#pragma unroll
            for (int r = 0; r < 4; ++r) {
                int row = lq * 4 + r;
                unsigned int hb = f2bf(fast_tanh(acc1[r] + b1v));
                unsigned int pk = hb | ((unsigned int)__shfl_xor((int)hb, 1) << 16);
                if (!(lm & 1)) {
                    *(unsigned int*)&h1[slw][row][((mychunk ^ (row & 7)) << 3) | (ncol & 7)] = pk;
                    exw[(size_t)row * 256 + (ncol >> 1)] = pk;
                }
            }
        }

        __syncthreads();   // drains vmcnt (all waves) before release post

        // --- G: single release-STORE post (monotonic, single writer) ---
        if (tid == 0)
            __hip_atomic_store(&flags[lblk], (unsigned int)(i + 1),
                               __ATOMIC_RELEASE, __HIP_MEMORY_SCOPE_AGENT);
    }

    // --- FC head: slice-0 blocks gather full h1_511 and reduce ---
    if (slice == 0) {
        if (poller) {   // final post value is 513
            while (__hip_atomic_load(&flags[g * 8 + ps],
                                     __ATOMIC_ACQUIRE, __HIP_MEMORY_SCOPE_AGENT) < 513u)
                ;
        }
        __syncthreads();
        if (dl) {    // h1_511 lives in hex slot 1, layer 1
            const uintx4* s = (const uintx4*)(hex + (size_t)((1 * 4 + g) * 2 + 1) * 4096);
#pragma unroll
            for (int j = 0; j < 4; ++j) {
                uintx4 v = s[j * 256 + tid];
                int r = j * 4 + rbase;
                *(uintx4*)&h1[1][r][(cch ^ (r & 7)) * 8] = v;
            }
        }
        __syncthreads();
        if (tid < 160) {
            int b = tid / 10, c = tid % 10;
            float s = bfc[c];
            for (int n = 0; n < 512; ++n) {
                unsigned short hb = h1[1][b][(((n >> 3) ^ (b & 7)) << 3) | (n & 7)];
                s += bf2f(hb) * wfc[c * 512 + n];
            }
            out[(size_t)(g * 16 + b) * 10 + c] = s;
        }
    }
}

extern "C" void kernel_launch(void* const* d_in, const int* in_sizes, int n_in,
                              void* d_out, int out_size, void* d_ws, size_t ws_size,
                              hipStream_t stream) {
    const float* x    = (const float*)d_in[0];
    const float* wih0 = (const float*)d_in[1];
    const float* whh0 = (const float*)d_in[2];
    const float* bih0 = (const float*)d_in[3];
    const float* bhh0 = (const float*)d_in[4];
    const float* wih1 = (const float*)d_in[5];
    const float* whh1 = (const float*)d_in[6];
    const float* bih1 = (const float*)d_in[7];
    const float* bhh1 = (const float*)d_in[8];
    const float* wfc  = (const float*)d_in[9];
    const float* bfc  = (const float*)d_in[10];
    float* out = (float*)d_out;

    unsigned short* wsb  = (unsigned short*)d_ws;
    unsigned short* xb   = wsb + OFS_XB;
    unsigned int* hex    = (unsigned int*)((char*)d_ws + HEX_BYTE);
    unsigned int* flags  = (unsigned int*)((char*)d_ws + FLAGS_BYTE);
    float* pre = (float*)((char*)d_ws + PRE_B);

    // 1. pack weights + convert x + zero flags
    prep_kernel<<<dim3(4545), dim3(256), 0, stream>>>(x, whh0, whh1, wih1, wih0, wsb);
    // 2. pre0 = x @ w_ih0^T + b_ih0 + b_hh0  (packed for fused kernel)
    proj_kernel<<<dim3(512), dim3(512), 0, stream>>>(xb, wsb + OFS_IH0, bih0, bhh0, pre, 8);
    // 3. fused 2-layer scan + FC head (grid 60: 32 active, XCD-local groups)
    fused_kernel<<<dim3(60), dim3(256), 0, stream>>>(
        pre, wsb + OFS_HH0, wsb + OFS_HH1, wsb + OFS_IH1,
        hex, flags, bih1, bhh1, wfc, bfc, out);
}

// Round 12
// 1795.582 us; speedup vs baseline: 3.9492x; 1.3313x over previous
//
#include <hip/hip_runtime.h>
#include <hip/hip_bf16.h>
#include <math.h>

// ---------------------------------------------------------------------------
// 2-layer tanh RNN, B=64 S=512 I=256 H=512, fp32 in/out, bf16 MFMA compute.
// Round 12: R11 base (2390 us, absmax 1.95e-3, XCD-local exchange, AGPR-
// pinned weights) + HAND-ROLLED INTRA-XCD SYNC. R11 showed removing the
// weight re-stream changed nothing -> the critical path is the exchange
// protocol itself. On gfx95x, agent-scope ACQUIRE lowers to buffer_inv
// (L2-wide invalidate, executed EVERY SPIN of every poll) and RELEASE to
// buffer_wbl2 (L2 writeback pass) -- O(k-cycles) each, ~5-8k cy/iter.
// Since R10 the exchange is XCD-local by construction, so the local L2 IS
// the coherence point and none of that maintenance is needed:
//   - polls/posts use RELAXED atomics (sc0, no inv/wb)
//   - ordering: __syncthreads() drains vmcnt(0) for all waves (hex stores
//     are write-through L1 -> in L2) BEFORE the flag store; consumer sees
//     flag only after data is in L2
//   - one cheap L1-only invalidate (buffer_inv sc0) per iteration after the
//     poll barrier so plain vectorized partner loads can't hit stale L1
//
// 32 active blocks = 4 groups x 8 slices, all 8 slices of group g on XCD g
// (physical blk: active iff (blk&7)<4; g=blk&7, slice=blk>>3; grid 60).
// Lag-1 pipeline per iter i (0..512): L0 step i (i<=511), L1 step i-1 (i>=1)
//   A: wave1 lanes0-6 poll 7 partner flags >= i (relaxed); barrier
//   B: buffer_inv sc0; issue partner hex loads (both layers) + pre_i
//   early: own k-tiles j=0..1
//   D: commit partner data to LDS slot i&1; barrier
//   main: k-tiles j=2..15
//   E: h0_{i+1}=tanh(acc0+pre) -> LDS slot (i+1)&1 + hex slot (i+1)&1
//   F: h1_{i-1}=tanh(acc1+b1)  -> LDS slot (i+1)&1 + hex slot (i+1)&1
//   G: barrier (drains all waves' vmcnt); wave0 relaxed-stores flags=i+1
//
// ws layout (bytes):
//   [0)        Wp_hh0  bf16 packed  512 KB
//   [524288)   Wp_hh1  bf16 packed  512 KB
//   [1048576)  Wp_ih1  bf16 packed  512 KB
//   [1572864)  Wp_ih0  bf16 packed  256 KB
//   [1835008)  hex     2 slots x 4 g x 2 layers x 16 x 256 u32 = 256 KB
//   [2097152)  xb      bf16 [32768][256]  16 MB
//   [18874368) flags   [32] u32
//   [52428800) pre     fp32 PACKED ((t*32+lblk)*256+tid)*4+r   64 MB
// ---------------------------------------------------------------------------

typedef __attribute__((ext_vector_type(8))) short  short8;
typedef __attribute__((ext_vector_type(4))) float  floatx4;
typedef __attribute__((ext_vector_type(4))) unsigned int uintx4;

#define MFMA_BF16(a, b, c) __builtin_amdgcn_mfma_f32_16x16x32_bf16((a), (b), (c), 0, 0, 0)

// offsets in u16 units for bf16 regions
#define OFS_HH0   ((size_t)0)
#define OFS_HH1   ((size_t)262144)
#define OFS_IH1   ((size_t)524288)
#define OFS_IH0   ((size_t)786432)
#define OFS_XB    ((size_t)1048576)
#define HEX_BYTE   ((size_t)1835008)
#define FLAGS_BYTE ((size_t)18874368)
#define PRE_B      ((size_t)52428800)

__device__ __forceinline__ unsigned short f2bf(float f) {
    unsigned u = __builtin_bit_cast(unsigned, f);
    u += 0x7fffu + ((u >> 16) & 1u);          // round-to-nearest-even
    return (unsigned short)(u >> 16);
}
__device__ __forceinline__ float bf2f(unsigned short h) {
    return __builtin_bit_cast(float, ((unsigned)h) << 16);
}
__device__ __forceinline__ float fast_tanh(float x) {
    float z = fminf(9.0f, fmaxf(-9.0f, x));
    float e = __builtin_amdgcn_exp2f(z * 2.88539008f);   // e^{2z}
    return (e - 1.0f) * __builtin_amdgcn_rcpf(e + 1.0f);
}
// L1-only invalidate (vector L1 of this CU). Cheap; does NOT touch L2.
__device__ __forceinline__ void inv_l1() {
    asm volatile("buffer_inv sc0" ::: "memory");
}

// ---- prep: pack weights into MFMA B-fragment order + convert x + flags ----
__device__ __forceinline__ void pack_w(const float* __restrict__ W,
                                       unsigned short* __restrict__ Wp,
                                       int KT, int idx) {
    int l  = idx & 63;
    int kt = (idx >> 6) % KT;
    int nt = (idx >> 6) / KT;
    int Kdim = KT * 32;
    int row = nt * 16 + (l & 15);
    int col = kt * 32 + (l >> 4) * 8;
    const float* s = W + (size_t)row * Kdim + col;
    short8 v;
#pragma unroll
    for (int j = 0; j < 8; ++j) v[j] = (short)f2bf(s[j]);
    *(short8*)(Wp + (size_t)idx * 8) = v;
}

__global__ void prep_kernel(const float* __restrict__ x,
                            const float* __restrict__ whh0,
                            const float* __restrict__ whh1,
                            const float* __restrict__ wih1,
                            const float* __restrict__ wih0,
                            unsigned short* __restrict__ wsb) {
    int blk = blockIdx.x, tid = threadIdx.x;
    if (blk < 128) {
        pack_w(whh0, wsb + OFS_HH0, 16, blk * 256 + tid);
    } else if (blk < 256) {
        pack_w(whh1, wsb + OFS_HH1, 16, (blk - 128) * 256 + tid);
    } else if (blk < 384) {
        pack_w(wih1, wsb + OFS_IH1, 16, (blk - 256) * 256 + tid);
    } else if (blk < 448) {
        pack_w(wih0, wsb + OFS_IH0, 8, (blk - 384) * 256 + tid);
    } else if (blk < 4544) {
        size_t e = ((size_t)(blk - 448) * 256 + tid) * 8;
        const float* s = x + e;
        short8 v;
#pragma unroll
        for (int j = 0; j < 8; ++j) v[j] = (short)f2bf(s[j]);
        *(short8*)(wsb + OFS_XB + e) = v;
    } else {
        if (tid < 32) ((unsigned int*)((char*)wsb + FLAGS_BYTE))[tid] = 0u;
    }
}

// ---- proj: pre0 = xb @ W_ih0^T + b_ih0 + b_hh0 -> fp32, PACKED for fused --
// fused mapping (logical block lblk = g*8 + slice):
// element (t,b,n): g=b>>4, br=b&15, slice=n>>6, w2=(n>>4)&3, lm2=n&15,
//   lq2=br>>2, r2=br&3; idx = ((t*32 + lblk)*256 + tid2)*4 + r2
__global__ __launch_bounds__(512) void proj_kernel(
        const unsigned short* __restrict__ A,
        const unsigned short* __restrict__ Wp,
        const float* __restrict__ bias1, const float* __restrict__ bias2,
        float* __restrict__ out, int KT) {
    int tid = threadIdx.x, blk = blockIdx.x;
    int w = tid >> 6, l = tid & 63, lm = l & 15, lq = l >> 4;
    int mg = w >> 1, nh = w & 1;
    int Kdim = KT * 32;
    int r0 = blk * 64 + mg * 16;

    floatx4 acc[16];
#pragma unroll
    for (int i = 0; i < 16; ++i) acc[i] = (floatx4)0.f;

    for (int kt = 0; kt < KT; ++kt) {
        short8 a = *(const short8*)(A + (size_t)(r0 + lm) * Kdim + kt * 32 + lq * 8);
#pragma unroll
        for (int i = 0; i < 16; ++i) {
            int ntg = nh * 16 + i;
            short8 b = *(const short8*)(Wp + (((size_t)ntg * KT + kt) * 64 + l) * 8);
            acc[i] = MFMA_BF16(a, b, acc[i]);
        }
    }
#pragma unroll
    for (int i = 0; i < 16; ++i) {
        int n = (nh * 16 + i) * 16 + lm;
        float bs = bias1[n] + bias2[n];
        int slice2 = n >> 6, w2 = (n >> 4) & 3, lm2 = n & 15;
#pragma unroll
        for (int r = 0; r < 4; ++r) {
            int row = r0 + lq * 4 + r;                  // row = b*512 + t
            int b = row >> 9, tt = row & 511;
            int g2 = b >> 4, br = b & 15;
            int lblk2 = g2 * 8 + slice2;
            int tid2 = w2 * 64 + (br >> 2) * 16 + lm2;
            size_t idx = (((size_t)tt * 32 + lblk2) * 256 + tid2) * 4 + (br & 3);
            out[idx] = acc[i][r] + bs;
        }
    }
}

// ---- fused 2-layer scan: 32 active blocks = 4 groups x 8 slices ----------
// Physical grid 60; active iff (blk&7)<4. XCD = blk%8 (round-robin, m09)
// => g = blk&7, slice = blk>>3 puts all 8 slices of group g on XCD g.
__global__ __launch_bounds__(256, 1) void fused_kernel(
        const float* __restrict__ pre,           // packed fp32 (layer-0 input proj)
        const unsigned short* __restrict__ Whh0, // packed bf16 KT=16
        const unsigned short* __restrict__ Whh1,
        const unsigned short* __restrict__ Wih1,
        unsigned int* __restrict__ hex,          // merged exchange, u32 col-pairs
        unsigned int* __restrict__ flags,        // [32]
        const float* __restrict__ bih1, const float* __restrict__ bhh1,
        const float* __restrict__ wfc, const float* __restrict__ bfc,
        float* __restrict__ out) {
    const int pblk = blockIdx.x;
    if ((pblk & 7) >= 4) return;                 // 28 dead residues exit at once

    __shared__ unsigned short h0[2][16][512];       // 32 KB, XOR-swizzled chunks
    __shared__ unsigned short h1[2][16][512];       // 32 KB

    const int tid = threadIdx.x;
    const int w = tid >> 6, l = tid & 63, lm = l & 15, lq = l >> 4;
    const int g = pblk & 7, slice = pblk >> 3;     // XCD-local: XCD(blk)=blk%8=g
    const int lblk = g * 8 + slice;                // logical id for pre/flags
    const int ntg = slice * 4 + w;            // global 16-col tile (0..31)
    const int ncol = ntg * 16 + lm;           // global col this thread produces
    const int s2 = slice * 2;                 // own k-tiles {s2, s2+1}

    // zero all h state (t<0 states and partner regions)
    {
        uintx4* z0 = (uintx4*)&h0[0][0][0];
        uintx4* z1 = (uintx4*)&h1[0][0][0];
        for (int i = tid; i < 1024; i += 256) { z0[i] = (uintx4)0u; z1[i] = (uintx4)0u; }
    }
    // Weights, PRE-ROTATED: breg?[j] = k-tile (s2+j)&15 (literal indices),
    // AGPR-pinned (non-rematerializable asm output closes the sinking hatch).
    short8 breg0[16], bregI[16], breg1[16];
#pragma unroll
    for (int j = 0; j < 16; ++j) {
        int kt = (s2 + j) & 15;
        size_t src = (((size_t)ntg * 16 + kt) * 64 + l) * 8;
        breg0[j] = *(const short8*)(Whh0 + src);
        bregI[j] = *(const short8*)(Wih1 + src);
        breg1[j] = *(const short8*)(Whh1 + src);
        asm volatile("" : "+a"(breg0[j]), "+a"(bregI[j]), "+a"(breg1[j]));
    }
    const float b1v = bih1[ncol] + bhh1[ncol];
    __syncthreads();

    // exchange-phase constants: thread t covers chunk c = t&63 (8 cols) at
    // rows r_j = j*4 + (t>>6), j=0..3  (per layer, per iter)
    const int cch = tid & 63;                      // logical chunk
    const int rbase = tid >> 6;                    // row offset within quad
    const bool dl = (cch >> 3) != slice;           // partner chunks only
    const bool poller = (w == 1) && (l < 7);
    const int ps = (slice + 1 + l) & 7;            // partner slice for lanes 0..6
    const int mychunk = ncol >> 3;

    for (int i = 0; i <= 512; ++i) {
        const int sl = i & 1, slw = sl ^ 1;

        // --- A: relaxed polls (sc0 L2 hits; NO buffer_inv per spin) ---
        if (poller && i >= 1) {
            unsigned int tgt = (unsigned int)i;
            while (__hip_atomic_load(&flags[g * 8 + ps],
                                     __ATOMIC_RELAXED, __HIP_MEMORY_SCOPE_AGENT) < tgt)
                ;
        }
        __syncthreads();

        // --- B: one cheap L1-only invalidate, then vectorized partner loads ---
        inv_l1();   // hex slots alternate every 2 iters; drop stale L1 lines
        const bool ld0 = dl && (i >= 1);
        const bool ld1 = dl && (i >= 2);
        uintx4 v0[4], v1[4];
        if (ld0) {
            const uintx4* s = (const uintx4*)(hex + (size_t)((sl * 4 + g) * 2 + 0) * 4096);
#pragma unroll
            for (int j = 0; j < 4; ++j) v0[j] = s[j * 256 + tid];
        }
        if (ld1) {
            const uintx4* s = (const uintx4*)(hex + (size_t)((sl * 4 + g) * 2 + 1) * 4096);
#pragma unroll
            for (int j = 0; j < 4; ++j) v1[j] = s[j * 256 + tid];
        }
        floatx4 pv = (floatx4)0.f;
        if (i <= 511)
            pv = *(const floatx4*)(pre + (((size_t)i * 32 + lblk) * 256 + tid) * 4);

        // --- early: own k-tiles j=0..1 (own cols already in LDS slot sl) ---
        floatx4 acc0 = (floatx4)0.f, acc1 = (floatx4)0.f;
#pragma unroll
        for (int j = 0; j < 2; ++j) {
            int kt = s2 + j;
            int ch = ((kt * 4 + lq) ^ (lm & 7)) << 3;
            short8 a = *(const short8*)&h0[sl][lm][ch];
            acc0 = MFMA_BF16(a, breg0[j], acc0);
            acc1 = MFMA_BF16(a, bregI[j], acc1);
            short8 a1 = *(const short8*)&h1[sl][lm][ch];
            acc1 = MFMA_BF16(a1, breg1[j], acc1);
        }

        // --- D: commit partner data (chunks c, rows j*4+rbase, swizzled) ---
        if (ld0) {
#pragma unroll
            for (int j = 0; j < 4; ++j) {
                int r = j * 4 + rbase;
                *(uintx4*)&h0[sl][r][(cch ^ (r & 7)) * 8] = v0[j];
            }
        }
        if (ld1) {
#pragma unroll
            for (int j = 0; j < 4; ++j) {
                int r = j * 4 + rbase;
                *(uintx4*)&h1[sl][r][(cch ^ (r & 7)) * 8] = v1[j];
            }
        }
        __syncthreads();

        // --- main: k-tiles j=2..15 (literal breg indices) ---
#pragma unroll
        for (int j = 2; j < 16; ++j) {
            int kt = (s2 + j) & 15;                // runtime only in LDS address
            int ch = ((kt * 4 + lq) ^ (lm & 7)) << 3;
            short8 a = *(const short8*)&h0[sl][lm][ch];
            acc0 = MFMA_BF16(a, breg0[j], acc0);
            acc1 = MFMA_BF16(a, bregI[j], acc1);
            short8 a1 = *(const short8*)&h1[sl][lm][ch];
            acc1 = MFMA_BF16(a1, breg1[j], acc1);
        }

        // --- E: layer-0 step i -> h0_{i+1} ---
        if (i <= 511) {
            unsigned int* exw = hex + (size_t)((slw * 4 + g) * 2 + 0) * 4096;
#pragma unroll
            for (int r = 0; r < 4; ++r) {
                int row = lq * 4 + r;
                unsigned int hb = f2bf(fast_tanh(acc0[r] + pv[r]));
                unsigned int pk = hb | ((unsigned int)__shfl_xor((int)hb, 1) << 16);
                if (!(lm & 1)) {
                    *(unsigned int*)&h0[slw][row][((mychunk ^ (row & 7)) << 3) | (ncol & 7)] = pk;
                    exw[(size_t)row * 256 + (ncol >> 1)] = pk;
                }
            }
        }

        // --- F: layer-1 step i-1 -> h1_{i-1} ---
        if (i >= 1) {
            unsigned int* exw = hex + (size_t)((slw * 4 + g) * 2 + 1) * 4096;
#pragma unroll
            for (int r = 0; r < 4; ++r) {
                int row = lq * 4 + r;
                unsigned int hb = f2bf(fast_tanh(acc1[r] + b1v));
                unsigned int pk = hb | ((unsigned int)__shfl_xor((int)hb, 1) << 16);
                if (!(lm & 1)) {
                    *(unsigned int*)&h1[slw][row][((mychunk ^ (row & 7)) << 3) | (ncol & 7)] = pk;
                    exw[(size_t)row * 256 + (ncol >> 1)] = pk;
                }
            }
        }

        __syncthreads();   // all waves' vmcnt drained => hex data is in L2
                           // (vector L1 is write-through) BEFORE the post

        // --- G: relaxed post (no buffer_wbl2; ordering via barrier above) ---
        if (tid == 0)
            __hip_atomic_store(&flags[lblk], (unsigned int)(i + 1),
                               __ATOMIC_RELAXED, __HIP_MEMORY_SCOPE_AGENT);
    }

    // --- FC head: slice-0 blocks gather full h1_511 and reduce ---
    if (slice == 0) {
        if (poller) {   // final post value is 513
            while (__hip_atomic_load(&flags[g * 8 + ps],
                                     __ATOMIC_RELAXED, __HIP_MEMORY_SCOPE_AGENT) < 513u)
                ;
        }
        __syncthreads();
        inv_l1();
        if (dl) {    // h1_511 lives in hex slot 1, layer 1
            const uintx4* s = (const uintx4*)(hex + (size_t)((1 * 4 + g) * 2 + 1) * 4096);
#pragma unroll
            for (int j = 0; j < 4; ++j) {
                uintx4 v = s[j * 256 + tid];
                int r = j * 4 + rbase;
                *(uintx4*)&h1[1][r][(cch ^ (r & 7)) * 8] = v;
            }
        }
        __syncthreads();
        if (tid < 160) {
            int b = tid / 10, c = tid % 10;
            float s = bfc[c];
            for (int n = 0; n < 512; ++n) {
                unsigned short hb = h1[1][b][(((n >> 3) ^ (b & 7)) << 3) | (n & 7)];
                s += bf2f(hb) * wfc[c * 512 + n];
            }
            out[(size_t)(g * 16 + b) * 10 + c] = s;
        }
    }
}

extern "C" void kernel_launch(void* const* d_in, const int* in_sizes, int n_in,
                              void* d_out, int out_size, void* d_ws, size_t ws_size,
                              hipStream_t stream) {
    const float* x    = (const float*)d_in[0];
    const float* wih0 = (const float*)d_in[1];
    const float* whh0 = (const float*)d_in[2];
    const float* bih0 = (const float*)d_in[3];
    const float* bhh0 = (const float*)d_in[4];
    const float* wih1 = (const float*)d_in[5];
    const float* whh1 = (const float*)d_in[6];
    const float* bih1 = (const float*)d_in[7];
    const float* bhh1 = (const float*)d_in[8];
    const float* wfc  = (const float*)d_in[9];
    const float* bfc  = (const float*)d_in[10];
    float* out = (float*)d_out;

    unsigned short* wsb  = (unsigned short*)d_ws;
    unsigned short* xb   = wsb + OFS_XB;
    unsigned int* hex    = (unsigned int*)((char*)d_ws + HEX_BYTE);
    unsigned int* flags  = (unsigned int*)((char*)d_ws + FLAGS_BYTE);
    float* pre = (float*)((char*)d_ws + PRE_B);

    // 1. pack weights + convert x + zero flags
    prep_kernel<<<dim3(4545), dim3(256), 0, stream>>>(x, whh0, whh1, wih1, wih0, wsb);
    // 2. pre0 = x @ w_ih0^T + b_ih0 + b_hh0  (packed for fused kernel)
    proj_kernel<<<dim3(512), dim3(512), 0, stream>>>(xb, wsb + OFS_IH0, bih0, bhh0, pre, 8);
    // 3. fused 2-layer scan + FC head (grid 60: 32 active, XCD-local groups)
    fused_kernel<<<dim3(60), dim3(256), 0, stream>>>(
        pre, wsb + OFS_HH0, wsb + OFS_HH1, wsb + OFS_IH1,
        hex, flags, bih1, bhh1, wfc, bfc, out);
}

// Round 13
// 1719.757 us; speedup vs baseline: 4.1233x; 1.0441x over previous
//
#include <hip/hip_runtime.h>
#include <hip/hip_bf16.h>
#include <math.h>

// ---------------------------------------------------------------------------
// 2-layer tanh RNN, B=64 S=512 I=256 H=512, fp32 in/out, bf16 MFMA compute.
// Round 13: R12 base (1796 us total, relaxed intra-XCD sync, AGPR weights)
// + LATENCY-HIDING PHASE RESTRUCTURE. R12's 7.4k cy/iter was ~75% stall:
// the consumer polled a flag the producer had JUST posted (zero slack), so
// post-propagation + detect + load RT were fully exposed, x3 barriers.
// Changes:
//   - L1 lag deepened to 2 (step i-2 at iter i): phase A (L1 compute,
//     ~1.2k cy) runs first on last-iter data; the h0 poll comes AFTER it,
//     targeting a post from the end of iter i-1 -> near-hit.
//   - h1 partner poll moved to END of iter (phase E), targeting posts from
//     partners' phase A of the SAME iter (~2.5k cy old) -> hit.
//   - Per-wave posts (own s_waitcnt vmcnt(0) + relaxed flag store) and
//     wave-local ballot polls over 7 partners x 4 waves = 28 flags.
//     Removes the post barrier: 2 barriers/iter instead of 3.
//   - L1's 32-long MFMA dependency chain split into accA+accB.
//   - FC head: every block assembles full h1_511 -> no post-loop exchange.
//
// Iteration i (0..513), slots cs=i&1, rs=(i+1)&1:
//   pv: load pre_i (issued first, consumed in D)
//   A (i>=2): L1 step i-2: read h0[rs](=h0_{i-1}), h1[rs](=h1_{i-3});
//      tanh -> own h1_{i-2} cols -> LDS h1[cs] + hex1[cs]
//   per-wave: vmcnt(0) drain; lane0 posts flags1[lblk*4+w]=i+1
//   C (1<=i<=512): ballot-poll flags0 >= i; inv_l1; load hex0[cs]
//      (partner h0_i); commit -> h0[cs]
//   beta1: __syncthreads
//   D (i<=511): L0 step i: read h0[cs]; tanh(acc0+pv) -> own h0_{i+1}
//      cols -> LDS h0[rs] + hex0[rs]
//   per-wave: vmcnt(0) drain; lane0 posts flags0[lblk*4+w]=i+1
//   E (i>=2): ballot-poll flags1 >= i+1; inv_l1; load hex1[cs]
//      (partner h1_{i-2}); commit -> h1[cs]
//   beta2: __syncthreads
//
// ws layout (bytes):
//   [0)        Wp_hh0  bf16 packed  512 KB
//   [524288)   Wp_hh1  bf16 packed  512 KB
//   [1048576)  Wp_ih1  bf16 packed  512 KB
//   [1572864)  Wp_ih0  bf16 packed  256 KB
//   [1835008)  hex     2 slots x 4 g x 2 layers x 16 x 256 u32 = 256 KB
//   [2097152)  xb      bf16 [32768][256]  16 MB
//   [18874368) flags   flags0[128] + flags1[128] u32 (per-wave)
//   [52428800) pre     fp32 PACKED ((t*32+lblk)*256+tid)*4+r   64 MB
// ---------------------------------------------------------------------------

typedef __attribute__((ext_vector_type(8))) short  short8;
typedef __attribute__((ext_vector_type(4))) float  floatx4;
typedef __attribute__((ext_vector_type(4))) unsigned int uintx4;

#define MFMA_BF16(a, b, c) __builtin_amdgcn_mfma_f32_16x16x32_bf16((a), (b), (c), 0, 0, 0)

// offsets in u16 units for bf16 regions
#define OFS_HH0   ((size_t)0)
#define OFS_HH1   ((size_t)262144)
#define OFS_IH1   ((size_t)524288)
#define OFS_IH0   ((size_t)786432)
#define OFS_XB    ((size_t)1048576)
#define HEX_BYTE   ((size_t)1835008)
#define FLAGS_BYTE ((size_t)18874368)
#define PRE_B      ((size_t)52428800)

__device__ __forceinline__ unsigned short f2bf(float f) {
    unsigned u = __builtin_bit_cast(unsigned, f);
    u += 0x7fffu + ((u >> 16) & 1u);          // round-to-nearest-even
    return (unsigned short)(u >> 16);
}
__device__ __forceinline__ float bf2f(unsigned short h) {
    return __builtin_bit_cast(float, ((unsigned)h) << 16);
}
__device__ __forceinline__ float fast_tanh(float x) {
    float z = fminf(9.0f, fmaxf(-9.0f, x));
    float e = __builtin_amdgcn_exp2f(z * 2.88539008f);   // e^{2z}
    return (e - 1.0f) * __builtin_amdgcn_rcpf(e + 1.0f);
}
// L1-only invalidate (vector L1 of this CU). Cheap; does NOT touch L2.
__device__ __forceinline__ void inv_l1() {
    asm volatile("buffer_inv sc0" ::: "memory");
}
// per-wave store drain (orders this wave's global stores before what follows)
__device__ __forceinline__ void drain_stores() {
    asm volatile("s_waitcnt vmcnt(0)" ::: "memory");
}

// ---- prep: pack weights into MFMA B-fragment order + convert x + flags ----
__device__ __forceinline__ void pack_w(const float* __restrict__ W,
                                       unsigned short* __restrict__ Wp,
                                       int KT, int idx) {
    int l  = idx & 63;
    int kt = (idx >> 6) % KT;
    int nt = (idx >> 6) / KT;
    int Kdim = KT * 32;
    int row = nt * 16 + (l & 15);
    int col = kt * 32 + (l >> 4) * 8;
    const float* s = W + (size_t)row * Kdim + col;
    short8 v;
#pragma unroll
    for (int j = 0; j < 8; ++j) v[j] = (short)f2bf(s[j]);
    *(short8*)(Wp + (size_t)idx * 8) = v;
}

__global__ void prep_kernel(const float* __restrict__ x,
                            const float* __restrict__ whh0,
                            const float* __restrict__ whh1,
                            const float* __restrict__ wih1,
                            const float* __restrict__ wih0,
                            unsigned short* __restrict__ wsb) {
    int blk = blockIdx.x, tid = threadIdx.x;
    if (blk < 128) {
        pack_w(whh0, wsb + OFS_HH0, 16, blk * 256 + tid);
    } else if (blk < 256) {
        pack_w(whh1, wsb + OFS_HH1, 16, (blk - 128) * 256 + tid);
    } else if (blk < 384) {
        pack_w(wih1, wsb + OFS_IH1, 16, (blk - 256) * 256 + tid);
    } else if (blk < 448) {
        pack_w(wih0, wsb + OFS_IH0, 8, (blk - 384) * 256 + tid);
    } else if (blk < 4544) {
        size_t e = ((size_t)(blk - 448) * 256 + tid) * 8;
        const float* s = x + e;
        short8 v;
#pragma unroll
        for (int j = 0; j < 8; ++j) v[j] = (short)f2bf(s[j]);
        *(short8*)(wsb + OFS_XB + e) = v;
    } else {
        ((unsigned int*)((char*)wsb + FLAGS_BYTE))[tid] = 0u;   // 256 u32
    }
}

// ---- proj: pre0 = xb @ W_ih0^T + b_ih0 + b_hh0 -> fp32, PACKED for fused --
__global__ __launch_bounds__(512) void proj_kernel(
        const unsigned short* __restrict__ A,
        const unsigned short* __restrict__ Wp,
        const float* __restrict__ bias1, const float* __restrict__ bias2,
        float* __restrict__ out, int KT) {
    int tid = threadIdx.x, blk = blockIdx.x;
    int w = tid >> 6, l = tid & 63, lm = l & 15, lq = l >> 4;
    int mg = w >> 1, nh = w & 1;
    int Kdim = KT * 32;
    int r0 = blk * 64 + mg * 16;

    floatx4 acc[16];
#pragma unroll
    for (int i = 0; i < 16; ++i) acc[i] = (floatx4)0.f;

    for (int kt = 0; kt < KT; ++kt) {
        short8 a = *(const short8*)(A + (size_t)(r0 + lm) * Kdim + kt * 32 + lq * 8);
#pragma unroll
        for (int i = 0; i < 16; ++i) {
            int ntg = nh * 16 + i;
            short8 b = *(const short8*)(Wp + (((size_t)ntg * KT + kt) * 64 + l) * 8);
            acc[i] = MFMA_BF16(a, b, acc[i]);
        }
    }
#pragma unroll
    for (int i = 0; i < 16; ++i) {
        int n = (nh * 16 + i) * 16 + lm;
        float bs = bias1[n] + bias2[n];
        int slice2 = n >> 6, w2 = (n >> 4) & 3, lm2 = n & 15;
#pragma unroll
        for (int r = 0; r < 4; ++r) {
            int row = r0 + lq * 4 + r;                  // row = b*512 + t
            int b = row >> 9, tt = row & 511;
            int g2 = b >> 4, br = b & 15;
            int lblk2 = g2 * 8 + slice2;
            int tid2 = w2 * 64 + (br >> 2) * 16 + lm2;
            size_t idx = (((size_t)tt * 32 + lblk2) * 256 + tid2) * 4 + (br & 3);
            out[idx] = acc[i][r] + bs;
        }
    }
}

// ---- fused 2-layer scan: 32 active blocks = 4 groups x 8 slices ----------
// Physical grid 60; active iff (blk&7)<4. XCD = blk%8 (round-robin, m09)
// => g = blk&7, slice = blk>>3 puts all 8 slices of group g on XCD g.
__global__ __launch_bounds__(256, 1) void fused_kernel(
        const float* __restrict__ pre,           // packed fp32 (layer-0 input proj)
        const unsigned short* __restrict__ Whh0, // packed bf16 KT=16
        const unsigned short* __restrict__ Whh1,
        const unsigned short* __restrict__ Wih1,
        unsigned int* __restrict__ hex,          // merged exchange, u32 col-pairs
        unsigned int* __restrict__ flags0,       // [128] per-wave
        unsigned int* __restrict__ flags1,       // [128] per-wave
        const float* __restrict__ bih1, const float* __restrict__ bhh1,
        const float* __restrict__ wfc, const float* __restrict__ bfc,
        float* __restrict__ out) {
    const int pblk = blockIdx.x;
    if ((pblk & 7) >= 4) return;                 // 28 dead residues exit at once

    __shared__ unsigned short h0[2][16][512];       // 32 KB, XOR-swizzled chunks
    __shared__ unsigned short h1[2][16][512];       // 32 KB

    const int tid = threadIdx.x;
    const int w = tid >> 6, l = tid & 63, lm = l & 15, lq = l >> 4;
    const int g = pblk & 7, slice = pblk >> 3;     // XCD-local: XCD(blk)=blk%8=g
    const int lblk = g * 8 + slice;                // logical id for pre/flags
    const int ntg = slice * 4 + w;            // global 16-col tile (0..31)
    const int ncol = ntg * 16 + lm;           // global col this thread produces
    const int s2 = slice * 2;                 // own k-tiles {s2, s2+1}

    // zero all h state (t<0 states and partner regions)
    {
        uintx4* z0 = (uintx4*)&h0[0][0][0];
        uintx4* z1 = (uintx4*)&h1[0][0][0];
        for (int i = tid; i < 1024; i += 256) { z0[i] = (uintx4)0u; z1[i] = (uintx4)0u; }
    }
    // Weights, PRE-ROTATED: breg?[j] = k-tile (s2+j)&15 (literal indices),
    // AGPR-pinned (non-rematerializable asm output closes the sinking hatch).
    short8 breg0[16], bregI[16], breg1[16];
#pragma unroll
    for (int j = 0; j < 16; ++j) {
        int kt = (s2 + j) & 15;
        size_t src = (((size_t)ntg * 16 + kt) * 64 + l) * 8;
        breg0[j] = *(const short8*)(Whh0 + src);
        bregI[j] = *(const short8*)(Wih1 + src);
        breg1[j] = *(const short8*)(Whh1 + src);
        asm volatile("" : "+a"(breg0[j]), "+a"(bregI[j]), "+a"(breg1[j]));
    }
    const float b1v = bih1[ncol] + bhh1[ncol];

    // exchange-phase constants: thread t covers chunk c = t&63 (8 cols) at
    // rows r_j = j*4 + (t>>6), j=0..3  (per layer, per iter)
    const int cch = tid & 63;                      // logical chunk
    const int rbase = tid >> 6;                    // row offset within quad
    const bool dl = (cch >> 3) != slice;           // partner chunks only
    const int mychunk = ncol >> 3;
    // ballot-poll lane mapping: lanes 0..27 -> partner pi = l>>2, wave pw = l&3
    const int pi = l >> 2, pw = l & 3;
    const int pslice = (slice + 1 + pi) & 7;
    const bool plane = (l < 28);
    const unsigned int* pf0 = flags0 + (plane ? ((g * 8 + pslice) * 4 + pw) : 0);
    const unsigned int* pf1 = flags1 + (plane ? ((g * 8 + pslice) * 4 + pw) : 0);

    __syncthreads();

    for (int i = 0; i <= 513; ++i) {
        const int cs = i & 1, rs = cs ^ 1;

        // pre load issued first (consumed in D, ~2k cy later)
        floatx4 pv = (floatx4)0.f;
        if (i <= 511)
            pv = *(const floatx4*)(pre + (((size_t)i * 32 + lblk) * 256 + tid) * 4);

        // --- A: L1 step i-2 (reads h0[rs]=h0_{i-1}, h1[rs]=h1_{i-3}) ---
        if (i >= 2) {
            floatx4 accA = (floatx4)0.f, accB = (floatx4)0.f;  // split chains
#pragma unroll
            for (int j = 0; j < 16; ++j) {
                int kt = (s2 + j) & 15;
                int ch = ((kt * 4 + lq) ^ (lm & 7)) << 3;
                short8 a0 = *(const short8*)&h0[rs][lm][ch];
                accA = MFMA_BF16(a0, bregI[j], accA);
                short8 a1 = *(const short8*)&h1[rs][lm][ch];
                accB = MFMA_BF16(a1, breg1[j], accB);
            }
            unsigned int* exw = hex + (size_t)((cs * 4 + g) * 2 + 1) * 4096;
#pragma unroll
            for (int r = 0; r < 4; ++r) {
                int row = lq * 4 + r;
                unsigned int hb = f2bf(fast_tanh(accA[r] + accB[r] + b1v));
                unsigned int pk = hb | ((unsigned int)__shfl_xor((int)hb, 1) << 16);
                if (!(lm & 1)) {
                    *(unsigned int*)&h1[cs][row][((mychunk ^ (row & 7)) << 3) | (ncol & 7)] = pk;
                    exw[(size_t)row * 256 + (ncol >> 1)] = pk;
                }
            }
        }
        // per-wave: drain own hex1 stores, post flags1 = i+1
        drain_stores();
        if (l == 0)
            __hip_atomic_store(&flags1[lblk * 4 + w], (unsigned int)(i + 1),
                               __ATOMIC_RELAXED, __HIP_MEMORY_SCOPE_AGENT);

        // --- C: h0 partner poll (posted end of iter i-1 -> near-hit) ---
        if (i >= 1 && i <= 512) {
            unsigned int tgt = (unsigned int)i;
            while (__ballot(plane && (__hip_atomic_load(pf0, __ATOMIC_RELAXED,
                        __HIP_MEMORY_SCOPE_AGENT) < tgt)) != 0ULL) {}
            inv_l1();
            if (dl) {
                const uintx4* s = (const uintx4*)(hex + (size_t)((cs * 4 + g) * 2 + 0) * 4096);
                uintx4 v0[4];
#pragma unroll
                for (int j = 0; j < 4; ++j) v0[j] = s[j * 256 + tid];
#pragma unroll
                for (int j = 0; j < 4; ++j) {
                    int r = j * 4 + rbase;
                    *(uintx4*)&h0[cs][r][(cch ^ (r & 7)) * 8] = v0[j];
                }
            }
        }
        __syncthreads();   // beta1: h0[cs] assembled; phase-A reads done

        // --- D: L0 step i (reads h0[cs]; writes h0[rs] own + hex0[rs]) ---
        if (i <= 511) {
            floatx4 acc0 = (floatx4)0.f;
#pragma unroll
            for (int j = 0; j < 16; ++j) {
                int kt = (s2 + j) & 15;
                int ch = ((kt * 4 + lq) ^ (lm & 7)) << 3;
                short8 a = *(const short8*)&h0[cs][lm][ch];
                acc0 = MFMA_BF16(a, breg0[j], acc0);
            }
            unsigned int* exw = hex + (size_t)((rs * 4 + g) * 2 + 0) * 4096;
#pragma unroll
            for (int r = 0; r < 4; ++r) {
                int row = lq * 4 + r;
                unsigned int hb = f2bf(fast_tanh(acc0[r] + pv[r]));
                unsigned int pk = hb | ((unsigned int)__shfl_xor((int)hb, 1) << 16);
                if (!(lm & 1)) {
                    *(unsigned int*)&h0[rs][row][((mychunk ^ (row & 7)) << 3) | (ncol & 7)] = pk;
                    exw[(size_t)row * 256 + (ncol >> 1)] = pk;
                }
            }
        }
        // per-wave: drain own hex0 stores, post flags0 = i+1
        drain_stores();
        if (l == 0)
            __hip_atomic_store(&flags0[lblk * 4 + w], (unsigned int)(i + 1),
                               __ATOMIC_RELAXED, __HIP_MEMORY_SCOPE_AGENT);

        // --- E: h1 partner poll (posted at partners' phase A, ~2.5k cy old) ---
        if (i >= 2) {
            unsigned int tgt = (unsigned int)(i + 1);
            while (__ballot(plane && (__hip_atomic_load(pf1, __ATOMIC_RELAXED,
                        __HIP_MEMORY_SCOPE_AGENT) < tgt)) != 0ULL) {}
            inv_l1();
            if (dl) {
                const uintx4* s = (const uintx4*)(hex + (size_t)((cs * 4 + g) * 2 + 1) * 4096);
                uintx4 v1[4];
#pragma unroll
                for (int j = 0; j < 4; ++j) v1[j] = s[j * 256 + tid];
#pragma unroll
                for (int j = 0; j < 4; ++j) {
                    int r = j * 4 + rbase;
                    *(uintx4*)&h1[cs][r][(cch ^ (r & 7)) * 8] = v1[j];
                }
            }
        }
        __syncthreads();   // beta2: h0[rs]/h1[cs] writes visible for next iter
    }

    // --- FC head: h1_511 fully assembled in h1[1] in EVERY block ---
    if (slice == 0 && tid < 160) {
        int b = tid / 10, c = tid % 10;
        float s = bfc[c];
        for (int n = 0; n < 512; ++n) {
            unsigned short hb = h1[1][b][(((n >> 3) ^ (b & 7)) << 3) | (n & 7)];
            s += bf2f(hb) * wfc[c * 512 + n];
        }
        out[(size_t)(g * 16 + b) * 10 + c] = s;
    }
}

extern "C" void kernel_launch(void* const* d_in, const int* in_sizes, int n_in,
                              void* d_out, int out_size, void* d_ws, size_t ws_size,
                              hipStream_t stream) {
    const float* x    = (const float*)d_in[0];
    const float* wih0 = (const float*)d_in[1];
    const float* whh0 = (const float*)d_in[2];
    const float* bih0 = (const float*)d_in[3];
    const float* bhh0 = (const float*)d_in[4];
    const float* wih1 = (const float*)d_in[5];
    const float* whh1 = (const float*)d_in[6];
    const float* bih1 = (const float*)d_in[7];
    const float* bhh1 = (const float*)d_in[8];
    const float* wfc  = (const float*)d_in[9];
    const float* bfc  = (const float*)d_in[10];
    float* out = (float*)d_out;

    unsigned short* wsb  = (unsigned short*)d_ws;
    unsigned short* xb   = wsb + OFS_XB;
    unsigned int* hex    = (unsigned int*)((char*)d_ws + HEX_BYTE);
    unsigned int* flags0 = (unsigned int*)((char*)d_ws + FLAGS_BYTE);
    unsigned int* flags1 = flags0 + 128;
    float* pre = (float*)((char*)d_ws + PRE_B);

    // 1. pack weights + convert x + zero flags (256 u32)
    prep_kernel<<<dim3(4545), dim3(256), 0, stream>>>(x, whh0, whh1, wih1, wih0, wsb);
    // 2. pre0 = x @ w_ih0^T + b_ih0 + b_hh0  (packed for fused kernel)
    proj_kernel<<<dim3(512), dim3(512), 0, stream>>>(xb, wsb + OFS_IH0, bih0, bhh0, pre, 8);
    // 3. fused 2-layer scan + FC head (grid 60: 32 active, XCD-local groups)
    fused_kernel<<<dim3(60), dim3(256), 0, stream>>>(
        pre, wsb + OFS_HH0, wsb + OFS_HH1, wsb + OFS_IH1,
        hex, flags0, flags1, bih1, bhh1, wfc, bfc, out);
}

// Round 14
// 1388.313 us; speedup vs baseline: 5.1077x; 1.2387x over previous
//
#include <hip/hip_runtime.h>
#include <hip/hip_bf16.h>
#include <math.h>

// ---------------------------------------------------------------------------
// 2-layer tanh RNN, B=64 S=512 I=256 H=512, fp32 in/out, bf16 MFMA compute.
// Round 14: R12 skeleton (proven best: merged flag, 1 poll + 1 post/iter,
// relaxed intra-XCD sync, XCD-local groups) + 2 WAVES/SIMD via K-SPLIT.
// R13 falsified "poll propagation latency dominates" (slack didn't help);
// the ~4k cy/iter unexplained stall matches zero-TLP at 1 wave/SIMD.
// Here: 512-thread blocks (8 waves, launch_bounds(512,2) -> 256 regs/wave).
// Wave-half wk=w>>2 owns k-tiles (s2+8*wk+j)&15, j=0..7: UNIFORM AGPR
// footprint WA/WB/WC[8] = 96 AGPR/wave (non-uniform layer-split would make
// 192 AGPR statically live -> VGPR starvation). Each SIMD hosts one lower +
// one upper wave -> latencies overlap. Cross-half fp32 reduction via padded
// LDS: lower posts acc1-partials, upper posts acc0-partials; after the R
// barrier, lower finalizes L0 (tanh+stores) while upper finalizes L1.
//
// Iteration i (0..512), sl=i&1, slw=sl^1  (R12 slot discipline verbatim):
//   A: wave1 lanes0-6 poll merged flags >= i; barrier; inv_l1
//   B: partner hex loads slot sl (L0 if i>=1, L1 if i>=2); pv (lower, i<=511)
//   early: lower waves j=0,1 (own k-tiles)
//   D: commit partner data -> h0[sl]/h1[sl]; barrier
//   main: lower j=2..7, upper j=0..7
//   R: lower writes acc1p=accA+accB, upper writes acc0p -> padded LDS; barrier
//   E (lower, i<=511): tanh(acc0p+red0+pv) -> h0[slw] + hex0[slw]
//   F (upper, i>=1):   tanh(accA+accB+red1+b1v) -> h1[slw] + hex1[slw]
//   barrier (drains vmcnt); tid0 relaxed-posts flags[lblk]=i+1
//
// ws layout (bytes): unchanged from R12/R13.
//   [0) Wp_hh0 512K | [524288) Wp_hh1 512K | [1048576) Wp_ih1 512K |
//   [1572864) Wp_ih0 256K | [1835008) hex 256K | [2097152) xb 16M |
//   [18874368) flags u32[256 zeroed, 32 used] | [52428800) pre 64M
// ---------------------------------------------------------------------------

typedef __attribute__((ext_vector_type(8))) short  short8;
typedef __attribute__((ext_vector_type(4))) float  floatx4;
typedef __attribute__((ext_vector_type(4))) unsigned int uintx4;

#define MFMA_BF16(a, b, c) __builtin_amdgcn_mfma_f32_16x16x32_bf16((a), (b), (c), 0, 0, 0)

// offsets in u16 units for bf16 regions
#define OFS_HH0   ((size_t)0)
#define OFS_HH1   ((size_t)262144)
#define OFS_IH1   ((size_t)524288)
#define OFS_IH0   ((size_t)786432)
#define OFS_XB    ((size_t)1048576)
#define HEX_BYTE   ((size_t)1835008)
#define FLAGS_BYTE ((size_t)18874368)
#define PRE_B      ((size_t)52428800)

__device__ __forceinline__ unsigned short f2bf(float f) {
    unsigned u = __builtin_bit_cast(unsigned, f);
    u += 0x7fffu + ((u >> 16) & 1u);          // round-to-nearest-even
    return (unsigned short)(u >> 16);
}
__device__ __forceinline__ float bf2f(unsigned short h) {
    return __builtin_bit_cast(float, ((unsigned)h) << 16);
}
__device__ __forceinline__ float fast_tanh(float x) {
    float z = fminf(9.0f, fmaxf(-9.0f, x));
    float e = __builtin_amdgcn_exp2f(z * 2.88539008f);   // e^{2z}
    return (e - 1.0f) * __builtin_amdgcn_rcpf(e + 1.0f);
}
// L1-only invalidate (vector L1 of this CU). Cheap; does NOT touch L2.
__device__ __forceinline__ void inv_l1() {
    asm volatile("buffer_inv sc0" ::: "memory");
}

// ---- prep: pack weights into MFMA B-fragment order + convert x + flags ----
__device__ __forceinline__ void pack_w(const float* __restrict__ W,
                                       unsigned short* __restrict__ Wp,
                                       int KT, int idx) {
    int l  = idx & 63;
    int kt = (idx >> 6) % KT;
    int nt = (idx >> 6) / KT;
    int Kdim = KT * 32;
    int row = nt * 16 + (l & 15);
    int col = kt * 32 + (l >> 4) * 8;
    const float* s = W + (size_t)row * Kdim + col;
    short8 v;
#pragma unroll
    for (int j = 0; j < 8; ++j) v[j] = (short)f2bf(s[j]);
    *(short8*)(Wp + (size_t)idx * 8) = v;
}

__global__ void prep_kernel(const float* __restrict__ x,
                            const float* __restrict__ whh0,
                            const float* __restrict__ whh1,
                            const float* __restrict__ wih1,
                            const float* __restrict__ wih0,
                            unsigned short* __restrict__ wsb) {
    int blk = blockIdx.x, tid = threadIdx.x;
    if (blk < 128) {
        pack_w(whh0, wsb + OFS_HH0, 16, blk * 256 + tid);
    } else if (blk < 256) {
        pack_w(whh1, wsb + OFS_HH1, 16, (blk - 128) * 256 + tid);
    } else if (blk < 384) {
        pack_w(wih1, wsb + OFS_IH1, 16, (blk - 256) * 256 + tid);
    } else if (blk < 448) {
        pack_w(wih0, wsb + OFS_IH0, 8, (blk - 384) * 256 + tid);
    } else if (blk < 4544) {
        size_t e = ((size_t)(blk - 448) * 256 + tid) * 8;
        const float* s = x + e;
        short8 v;
#pragma unroll
        for (int j = 0; j < 8; ++j) v[j] = (short)f2bf(s[j]);
        *(short8*)(wsb + OFS_XB + e) = v;
    } else {
        ((unsigned int*)((char*)wsb + FLAGS_BYTE))[tid] = 0u;   // 256 u32
    }
}

// ---- proj: pre0 = xb @ W_ih0^T + b_ih0 + b_hh0 -> fp32, PACKED for fused --
// (layout targets the LOWER 256 threads of the fused kernel: unchanged)
__global__ __launch_bounds__(512) void proj_kernel(
        const unsigned short* __restrict__ A,
        const unsigned short* __restrict__ Wp,
        const float* __restrict__ bias1, const float* __restrict__ bias2,
        float* __restrict__ out, int KT) {
    int tid = threadIdx.x, blk = blockIdx.x;
    int w = tid >> 6, l = tid & 63, lm = l & 15, lq = l >> 4;
    int mg = w >> 1, nh = w & 1;
    int Kdim = KT * 32;
    int r0 = blk * 64 + mg * 16;

    floatx4 acc[16];
#pragma unroll
    for (int i = 0; i < 16; ++i) acc[i] = (floatx4)0.f;

    for (int kt = 0; kt < KT; ++kt) {
        short8 a = *(const short8*)(A + (size_t)(r0 + lm) * Kdim + kt * 32 + lq * 8);
#pragma unroll
        for (int i = 0; i < 16; ++i) {
            int ntg = nh * 16 + i;
            short8 b = *(const short8*)(Wp + (((size_t)ntg * KT + kt) * 64 + l) * 8);
            acc[i] = MFMA_BF16(a, b, acc[i]);
        }
    }
#pragma unroll
    for (int i = 0; i < 16; ++i) {
        int n = (nh * 16 + i) * 16 + lm;
        float bs = bias1[n] + bias2[n];
        int slice2 = n >> 6, w2 = (n >> 4) & 3, lm2 = n & 15;
#pragma unroll
        for (int r = 0; r < 4; ++r) {
            int row = r0 + lq * 4 + r;                  // row = b*512 + t
            int b = row >> 9, tt = row & 511;
            int g2 = b >> 4, br = b & 15;
            int lblk2 = g2 * 8 + slice2;
            int tid2 = w2 * 64 + (br >> 2) * 16 + lm2;
            size_t idx = (((size_t)tt * 32 + lblk2) * 256 + tid2) * 4 + (br & 3);
            out[idx] = acc[i][r] + bs;
        }
    }
}

// ---- fused 2-layer scan: 32 active blocks x 512 threads, k-split --------
// Physical grid 60; active iff (blk&7)<4. XCD = blk%8 (round-robin, m09)
// => g = blk&7, slice = blk>>3 puts all 8 slices of group g on XCD g.
__global__ __launch_bounds__(512, 2) void fused_kernel(
        const float* __restrict__ pre,           // packed fp32 (layer-0 input proj)
        const unsigned short* __restrict__ Whh0, // packed bf16 KT=16
        const unsigned short* __restrict__ Whh1,
        const unsigned short* __restrict__ Wih1,
        unsigned int* __restrict__ hex,          // merged exchange, u32 col-pairs
        unsigned int* __restrict__ flags,        // [32] merged per-block
        const float* __restrict__ bih1, const float* __restrict__ bhh1,
        const float* __restrict__ wfc, const float* __restrict__ bfc,
        float* __restrict__ out) {
    const int pblk = blockIdx.x;
    if ((pblk & 7) >= 4) return;                 // 28 dead residues exit at once

    __shared__ unsigned short h0[2][16][512];       // 32 KB, XOR-swizzled chunks
    __shared__ unsigned short h1[2][16][512];       // 32 KB
    __shared__ float red0[256][5];                  // acc0 partials (upper->lower)
    __shared__ float red1[256][5];                  // acc1 partials (lower->upper)

    const int tid = threadIdx.x;
    const int w = tid >> 6, l = tid & 63, lm = l & 15, lq = l >> 4;
    const int wk = w >> 2, wn = w & 3;             // k-half, n-tile within slice
    const int g = pblk & 7, slice = pblk >> 3;     // XCD-local: XCD(blk)=blk%8=g
    const int lblk = g * 8 + slice;                // logical id for pre/flags
    const int ntg = slice * 4 + wn;           // global 16-col tile (0..31)
    const int ncol = ntg * 16 + lm;           // global col this thread produces
    const int s2 = slice * 2;                 // own k-tiles {s2, s2+1}
    const int rid = tid & 255;                // reduction partner index

    // zero all h state (t<0 states and partner regions)
    {
        uintx4* z0 = (uintx4*)&h0[0][0][0];
        uintx4* z1 = (uintx4*)&h1[0][0][0];
        for (int i = tid; i < 1024; i += 512) { z0[i] = (uintx4)0u; z1[i] = (uintx4)0u; }
    }
    // Weights, PRE-ROTATED per k-half: W?[j] = k-tile (s2 + 8*wk + j)&15.
    // UNIFORM 3x8 frags = 96 AGPR static footprint for every wave.
    short8 WA[8], WB[8], WC[8];
#pragma unroll
    for (int j = 0; j < 8; ++j) {
        int kt = (s2 + wk * 8 + j) & 15;
        size_t src = (((size_t)ntg * 16 + kt) * 64 + l) * 8;
        WA[j] = *(const short8*)(Whh0 + src);
        WB[j] = *(const short8*)(Wih1 + src);
        WC[j] = *(const short8*)(Whh1 + src);
        asm volatile("" : "+a"(WA[j]), "+a"(WB[j]), "+a"(WC[j]));
    }
    const float b1v = bih1[ncol] + bhh1[ncol];

    // exchange constants: thread covers chunk cch at rows rbase, rbase+8
    const int cch = tid & 63;
    const int rbase = tid >> 6;                    // 0..7
    const bool dl = (cch >> 3) != slice;           // partner chunks only
    const bool poller = (w == 1) && (l < 7);
    const int ps = (slice + 1 + l) & 7;            // partner slice, lanes 0..6
    const int mychunk = ncol >> 3;

    __syncthreads();

    for (int i = 0; i <= 512; ++i) {
        const int sl = i & 1, slw = sl ^ 1;

        // --- A: merged-flag poll (relaxed, L2 hits) ---
        if (poller && i >= 1) {
            unsigned int tgt = (unsigned int)i;
            while (__hip_atomic_load(&flags[g * 8 + ps],
                                     __ATOMIC_RELAXED, __HIP_MEMORY_SCOPE_AGENT) < tgt)
                ;
        }
        __syncthreads();
        inv_l1();

        // --- B: partner loads (slot sl) + pv (lower waves) ---
        const bool ld0 = dl && (i >= 1);
        const bool ld1 = dl && (i >= 2);
        uintx4 v00, v01, v10, v11;
        if (ld0) {
            const uintx4* s = (const uintx4*)(hex + (size_t)((sl * 4 + g) * 2 + 0) * 4096);
            v00 = s[rbase * 64 + cch];
            v01 = s[(rbase + 8) * 64 + cch];
        }
        if (ld1) {
            const uintx4* s = (const uintx4*)(hex + (size_t)((sl * 4 + g) * 2 + 1) * 4096);
            v10 = s[rbase * 64 + cch];
            v11 = s[(rbase + 8) * 64 + cch];
        }
        floatx4 pv = (floatx4)0.f;
        if (wk == 0 && i <= 511)
            pv = *(const floatx4*)(pre + (((size_t)i * 32 + lblk) * 256 + tid) * 4);

        // --- early: lower waves, own k-tiles j=0,1 ---
        floatx4 acc0p = (floatx4)0.f, accA = (floatx4)0.f, accB = (floatx4)0.f;
        if (wk == 0) {
#pragma unroll
            for (int j = 0; j < 2; ++j) {
                int kt = s2 + j;
                int ch = ((kt * 4 + lq) ^ (lm & 7)) << 3;
                short8 a = *(const short8*)&h0[sl][lm][ch];
                acc0p = MFMA_BF16(a, WA[j], acc0p);
                accA  = MFMA_BF16(a, WB[j], accA);
                short8 a1 = *(const short8*)&h1[sl][lm][ch];
                accB  = MFMA_BF16(a1, WC[j], accB);
            }
        }

        // --- D: commit partner data ---
        if (ld0) {
            int r0r = rbase, r1r = rbase + 8;
            *(uintx4*)&h0[sl][r0r][(cch ^ (r0r & 7)) * 8] = v00;
            *(uintx4*)&h0[sl][r1r][(cch ^ (r1r & 7)) * 8] = v01;
        }
        if (ld1) {
            int r0r = rbase, r1r = rbase + 8;
            *(uintx4*)&h1[sl][r0r][(cch ^ (r0r & 7)) * 8] = v10;
            *(uintx4*)&h1[sl][r1r][(cch ^ (r1r & 7)) * 8] = v11;
        }
        __syncthreads();

        // --- main: lower j=2..7, upper j=0..7 (literal W indices) ---
        if (wk == 0) {
#pragma unroll
            for (int j = 2; j < 8; ++j) {
                int kt = (s2 + j) & 15;
                int ch = ((kt * 4 + lq) ^ (lm & 7)) << 3;
                short8 a = *(const short8*)&h0[sl][lm][ch];
                acc0p = MFMA_BF16(a, WA[j], acc0p);
                accA  = MFMA_BF16(a, WB[j], accA);
                short8 a1 = *(const short8*)&h1[sl][lm][ch];
                accB  = MFMA_BF16(a1, WC[j], accB);
            }
        } else {
#pragma unroll
            for (int j = 0; j < 8; ++j) {
                int kt = (s2 + 8 + j) & 15;
                int ch = ((kt * 4 + lq) ^ (lm & 7)) << 3;
                short8 a = *(const short8*)&h0[sl][lm][ch];
                acc0p = MFMA_BF16(a, WA[j], acc0p);
                accA  = MFMA_BF16(a, WB[j], accA);
                short8 a1 = *(const short8*)&h1[sl][lm][ch];
                accB  = MFMA_BF16(a1, WC[j], accB);
            }
        }

        // --- R: cross-half partial exchange (padded LDS, conflict-free) ---
        if (wk == 0) {
#pragma unroll
            for (int r = 0; r < 4; ++r) red1[rid][r] = accA[r] + accB[r];
        } else {
#pragma unroll
            for (int r = 0; r < 4; ++r) red0[rid][r] = acc0p[r];
        }
        __syncthreads();

        // --- E: lower waves finalize L0 step i -> h0[slw] + hex0[slw] ---
        if (wk == 0 && i <= 511) {
            unsigned int* exw = hex + (size_t)((slw * 4 + g) * 2 + 0) * 4096;
#pragma unroll
            for (int r = 0; r < 4; ++r) {
                int row = lq * 4 + r;
                unsigned int hb = f2bf(fast_tanh(acc0p[r] + red0[rid][r] + pv[r]));
                unsigned int pk = hb | ((unsigned int)__shfl_xor((int)hb, 1) << 16);
                if (!(lm & 1)) {
                    *(unsigned int*)&h0[slw][row][((mychunk ^ (row & 7)) << 3) | (ncol & 7)] = pk;
                    exw[(size_t)row * 256 + (ncol >> 1)] = pk;
                }
            }
        }
        // --- F: upper waves finalize L1 step i-1 -> h1[slw] + hex1[slw] ---
        if (wk == 1 && i >= 1) {
            unsigned int* exw = hex + (size_t)((slw * 4 + g) * 2 + 1) * 4096;
#pragma unroll
            for (int r = 0; r < 4; ++r) {
                int row = lq * 4 + r;
                unsigned int hb =
                    f2bf(fast_tanh(accA[r] + accB[r] + red1[rid][r] + b1v));
                unsigned int pk = hb | ((unsigned int)__shfl_xor((int)hb, 1) << 16);
                if (!(lm & 1)) {
                    *(unsigned int*)&h1[slw][row][((mychunk ^ (row & 7)) << 3) | (ncol & 7)] = pk;
                    exw[(size_t)row * 256 + (ncol >> 1)] = pk;
                }
            }
        }

        __syncthreads();   // drains all waves' vmcnt => hex data in L2 pre-post

        // --- post: merged flag, single writer, relaxed ---
        if (tid == 0)
            __hip_atomic_store(&flags[lblk], (unsigned int)(i + 1),
                               __ATOMIC_RELAXED, __HIP_MEMORY_SCOPE_AGENT);
    }

    // --- FC head: slice-0 blocks gather full h1 final state (R12 tail) ---
    if (slice == 0) {
        if (poller) {   // final post value is 513
            while (__hip_atomic_load(&flags[g * 8 + ps],
                                     __ATOMIC_RELAXED, __HIP_MEMORY_SCOPE_AGENT) < 513u)
                ;
        }
        __syncthreads();
        inv_l1();
        if (dl) {    // final h1 lives in hex slot 1, layer 1
            const uintx4* s = (const uintx4*)(hex + (size_t)((1 * 4 + g) * 2 + 1) * 4096);
            uintx4 a = s[rbase * 64 + cch];
            uintx4 b = s[(rbase + 8) * 64 + cch];
            int r0r = rbase, r1r = rbase + 8;
            *(uintx4*)&h1[1][r0r][(cch ^ (r0r & 7)) * 8] = a;
            *(uintx4*)&h1[1][r1r][(cch ^ (r1r & 7)) * 8] = b;
        }
        __syncthreads();
        if (tid < 160) {
            int b = tid / 10, c = tid % 10;
            float s = bfc[c];
            for (int n = 0; n < 512; ++n) {
                unsigned short hb = h1[1][b][(((n >> 3) ^ (b & 7)) << 3) | (n & 7)];
                s += bf2f(hb) * wfc[c * 512 + n];
            }
            out[(size_t)(g * 16 + b) * 10 + c] = s;
        }
    }
}

extern "C" void kernel_launch(void* const* d_in, const int* in_sizes, int n_in,
                              void* d_out, int out_size, void* d_ws, size_t ws_size,
                              hipStream_t stream) {
    const float* x    = (const float*)d_in[0];
    const float* wih0 = (const float*)d_in[1];
    const float* whh0 = (const float*)d_in[2];
    const float* bih0 = (const float*)d_in[3];
    const float* bhh0 = (const float*)d_in[4];
    const float* wih1 = (const float*)d_in[5];
    const float* whh1 = (const float*)d_in[6];
    const float* bih1 = (const float*)d_in[7];
    const float* bhh1 = (const float*)d_in[8];
    const float* wfc  = (const float*)d_in[9];
    const float* bfc  = (const float*)d_in[10];
    float* out = (float*)d_out;

    unsigned short* wsb  = (unsigned short*)d_ws;
    unsigned short* xb   = wsb + OFS_XB;
    unsigned int* hex    = (unsigned int*)((char*)d_ws + HEX_BYTE);
    unsigned int* flags  = (unsigned int*)((char*)d_ws + FLAGS_BYTE);
    float* pre = (float*)((char*)d_ws + PRE_B);

    // 1. pack weights + convert x + zero flags
    prep_kernel<<<dim3(4545), dim3(256), 0, stream>>>(x, whh0, whh1, wih1, wih0, wsb);
    // 2. pre0 = x @ w_ih0^T + b_ih0 + b_hh0  (packed for fused kernel)
    proj_kernel<<<dim3(512), dim3(512), 0, stream>>>(xb, wsb + OFS_IH0, bih0, bhh0, pre, 8);
    // 3. fused 2-layer scan + FC head (grid 60: 32 active, XCD-local groups)
    fused_kernel<<<dim3(60), dim3(512), 0, stream>>>(
        pre, wsb + OFS_HH0, wsb + OFS_HH1, wsb + OFS_IH1,
        hex, flags, bih1, bhh1, wfc, bfc, out);
}